// Round 6
// baseline (689.817 us; speedup 1.0000x reference)
//
#include <hip/hip_runtime.h>
#include <hip/hip_bf16.h>

#define N_NODES 50000
#define N_EDGES 800000
#define DIM 96
#define CH 24  // DIM/4 float4 chunks per row

#define SCAN_CHUNK 1024
#define SCAN_NB ((N_NODES + SCAN_CHUNK - 1) / SCAN_CHUNK)  // 49

// ---------------- dtype detection (on-device, graph-capture safe) ----------------
// flags[0] = h is bf16, flags[1] = W/b are bf16, flags[2] = indices are int64
// Measured R3-R5: this instance is fp32 + int64; detector kept for safety.

__global__ void detect_kernel(const unsigned* __restrict__ hw,
                              const unsigned* __restrict__ ww,
                              const unsigned* __restrict__ sw,
                              int* __restrict__ flags) {
    int t = threadIdx.x;
    if (t == 0 || t == 1) {
        const unsigned* p = (t == 0) ? hw : ww;
        int good = 0;
        for (int i = 0; i < 128; ++i) {
            unsigned w = p[i];
            unsigned lo = w & 0xFFFFu, hi = w >> 16;
            unsigned e0 = (lo >> 7) & 0xFF, e1 = (hi >> 7) & 0xFF;
            if (lo == 0 || (e0 >= 100 && e0 <= 140)) ++good;
            if (hi == 0 || (e1 >= 100 && e1 <= 140)) ++good;
        }
        flags[t] = (good >= 226) ? 1 : 0;
    } else if (t == 2) {
        int zeros = 0;
        for (int i = 0; i < 64; ++i)
            if (sw[2 * i + 1] == 0u) ++zeros;
        flags[2] = (zeros >= 60) ? 1 : 0;
    }
}

__device__ __forceinline__ int load_idx(const int* __restrict__ p, int e, int is64) {
    return p[is64 ? (e << 1) : e];
}

// ---------------- degrees + dst slot (single atomic pass) ----------------
// eslot[e] = arrival order of edge e within its dst bucket -> atomic-free placement.

__global__ __launch_bounds__(256) void deg_kernel(const int* __restrict__ src,
                                                  const int* __restrict__ dst,
                                                  int* __restrict__ degS,
                                                  int* __restrict__ degD,
                                                  int* __restrict__ eslot,
                                                  const int* __restrict__ flags) {
    int is64 = flags[2];
    int e = blockIdx.x * 256 + threadIdx.x;
    if (e < N_EDGES) {
        atomicAdd(&degS[load_idx(src, e, is64)], 1);
        eslot[e] = atomicAdd(&degD[load_idx(dst, e, is64)], 1);
    }
}

// ---------------- hierarchical exclusive scan of degD -> rowptr (+ norms) ----------------

__global__ __launch_bounds__(256) void scan_p1(const int* __restrict__ degS,
                                               const int* __restrict__ degD,
                                               float* __restrict__ normS,
                                               float* __restrict__ normD,
                                               int* __restrict__ psum) {
    __shared__ int red[256];
    int b = blockIdx.x, t = threadIdx.x;
    int base = b * SCAN_CHUNK + t * 4;
    int s = 0;
#pragma unroll
    for (int i = 0; i < 4; ++i) {
        int idx = base + i;
        if (idx < N_NODES) {
            int dd = degD[idx];
            s += dd;
            normD[idx] = rsqrtf((float)max(dd, 1));
            normS[idx] = rsqrtf((float)max(degS[idx], 1));
        }
    }
    red[t] = s;
    __syncthreads();
    for (int off = 128; off > 0; off >>= 1) {
        if (t < off) red[t] += red[t + off];
        __syncthreads();
    }
    if (t == 0) psum[b] = red[0];
}

__global__ __launch_bounds__(64) void scan_p2(const int* __restrict__ psum,
                                              int* __restrict__ poff) {
    __shared__ int s[64];
    int t = threadIdx.x;
    int v = (t < SCAN_NB) ? psum[t] : 0;
    s[t] = v;
    __syncthreads();
    for (int off = 1; off < 64; off <<= 1) {
        int u = (t >= off) ? s[t - off] : 0;
        __syncthreads();
        s[t] += u;
        __syncthreads();
    }
    if (t < SCAN_NB) poff[t] = s[t] - v;
}

__global__ __launch_bounds__(256) void scan_p3(const int* __restrict__ degD,
                                               const int* __restrict__ poff,
                                               int* __restrict__ rowptr) {
    __shared__ int s[256];
    int b = blockIdx.x, t = threadIdx.x;
    int base = b * SCAN_CHUNK + t * 4;
    int d[4];
    int tsum = 0;
#pragma unroll
    for (int i = 0; i < 4; ++i) {
        int idx = base + i;
        d[i] = (idx < N_NODES) ? degD[idx] : 0;
        tsum += d[i];
    }
    s[t] = tsum;
    __syncthreads();
    for (int off = 1; off < 256; off <<= 1) {
        int u = (t >= off) ? s[t - off] : 0;
        __syncthreads();
        s[t] += u;
        __syncthreads();
    }
    int run = poff[b] + s[t] - tsum;
#pragma unroll
    for (int i = 0; i < 4; ++i) {
        int idx = base + i;
        if (idx < N_NODES) { rowptr[idx] = run; run += d[i]; }
    }
    if (b == 0 && t == 0) rowptr[N_NODES] = N_EDGES;
}

// ---------------- atomic-free placement: esrc[rowptr[d]+eslot[e]] = s ----------------

__global__ __launch_bounds__(256) void place_kernel(const int* __restrict__ src,
                                                    const int* __restrict__ dst,
                                                    const int* __restrict__ rowptr,
                                                    const int* __restrict__ eslot,
                                                    int* __restrict__ esrc,
                                                    const int* __restrict__ flags) {
    int is64 = flags[2];
    int e = blockIdx.x * 256 + threadIdx.x;
    if (e < N_EDGES) {
        int d = load_idx(dst, e, is64);
        int s = load_idx(src, e, is64);
        esrc[rowptr[d] + eslot[e]] = s;
    }
}

// ---------------- fused gather + GEMM ----------------
// Per block: 64 dst rows. Phase 1: each (row,chunk) item accumulates its CSR edge
// list in registers (x[src] prescaled by normS; layer 0 reads h * normS[s] directly),
// scales by normD, stores to LDS Bs. Phase 2: 64x96 @ 96x96 GEMM from LDS,
// relu+bias epilogue; non-last layers fold normS into the output.

template <bool FIRST, bool LAST>
__global__ __launch_bounds__(256) void fused_kernel(const void* __restrict__ X,
                                                    const float* __restrict__ normS,
                                                    const float* __restrict__ normD,
                                                    const int* __restrict__ rowptr,
                                                    const int* __restrict__ esrc,
                                                    const void* __restrict__ W,
                                                    const void* __restrict__ bias,
                                                    float* __restrict__ outF,
                                                    void* __restrict__ outLast,
                                                    const int* __restrict__ flags) {
    __shared__ float Ws[DIM * DIM];      // 36864 B
    __shared__ float Bs[64][DIM + 1];    // 24832 B
    __shared__ float bs[DIM];

    int wbf = flags[1];
    if (wbf) {
        for (int i = threadIdx.x; i < DIM * DIM; i += 256)
            Ws[i] = __bfloat162float(((const __hip_bfloat16*)W)[i]);
        if (threadIdx.x < DIM)
            bs[threadIdx.x] = __bfloat162float(((const __hip_bfloat16*)bias)[threadIdx.x]);
    } else {
        for (int i = threadIdx.x; i < DIM * DIM; i += 256)
            Ws[i] = ((const float*)W)[i];
        if (threadIdx.x < DIM)
            bs[threadIdx.x] = ((const float*)bias)[threadIdx.x];
    }

    int hbf = FIRST ? flags[0] : 0;
    int row0 = blockIdx.x * 64;

    // Phase 1: gather into LDS
    for (int i = threadIdx.x; i < 64 * CH; i += 256) {
        int r = i / CH;
        int c4 = i - r * CH;
        int n = row0 + r;
        float4 acc = make_float4(0.f, 0.f, 0.f, 0.f);
        if (n < N_NODES) {
            int beg = rowptr[n], end = rowptr[n + 1];
            if (FIRST && hbf) {
                for (int k = beg; k < end; ++k) {
                    int s = esrc[k];
                    const __hip_bfloat16* hp = (const __hip_bfloat16*)X + (size_t)s * DIM + c4 * 4;
                    float ns = normS[s];
                    acc.x += __bfloat162float(hp[0]) * ns;
                    acc.y += __bfloat162float(hp[1]) * ns;
                    acc.z += __bfloat162float(hp[2]) * ns;
                    acc.w += __bfloat162float(hp[3]) * ns;
                }
            } else if (FIRST) {
                for (int k = beg; k < end; ++k) {
                    int s = esrc[k];
                    float4 v = ((const float4*)X)[s * CH + c4];
                    float ns = normS[s];
                    acc.x += v.x * ns; acc.y += v.y * ns;
                    acc.z += v.z * ns; acc.w += v.w * ns;
                }
            } else {
                for (int k = beg; k < end; ++k) {
                    int s = esrc[k];
                    float4 v = ((const float4*)X)[s * CH + c4];
                    acc.x += v.x; acc.y += v.y; acc.z += v.z; acc.w += v.w;
                }
            }
            float nd = normD[n];
            acc.x *= nd; acc.y *= nd; acc.z *= nd; acc.w *= nd;
        }
        float* bp = &Bs[r][c4 * 4];
        bp[0] = acc.x; bp[1] = acc.y; bp[2] = acc.z; bp[3] = acc.w;
    }
    __syncthreads();

    // Phase 2: GEMM
    int cg = threadIdx.x & 7;   // 8 col-groups of 12
    int rg = threadIdx.x >> 3;  // 32 row-groups of 2
    int r0 = rg * 2;
    int c0 = cg * 12;

    float acc0[12], acc1[12];
#pragma unroll
    for (int j = 0; j < 12; ++j) { acc0[j] = 0.f; acc1[j] = 0.f; }

    for (int k = 0; k < DIM; ++k) {
        float a0 = Bs[r0][k];
        float a1 = Bs[r0 + 1][k];
        const float4* w4 = (const float4*)&Ws[k * DIM + c0];
#pragma unroll
        for (int j4 = 0; j4 < 3; ++j4) {
            float4 w = w4[j4];
            acc0[j4 * 4 + 0] += a0 * w.x;
            acc0[j4 * 4 + 1] += a0 * w.y;
            acc0[j4 * 4 + 2] += a0 * w.z;
            acc0[j4 * 4 + 3] += a0 * w.w;
            acc1[j4 * 4 + 0] += a1 * w.x;
            acc1[j4 * 4 + 1] += a1 * w.y;
            acc1[j4 * 4 + 2] += a1 * w.z;
            acc1[j4 * 4 + 3] += a1 * w.w;
        }
    }

    int obf = flags[0];
#pragma unroll
    for (int rr = 0; rr < 2; ++rr) {
        int gr = row0 + r0 + rr;
        if (gr >= N_NODES) continue;
        const float* accp = rr ? acc1 : acc0;
        float ns = LAST ? 1.f : normS[gr];
#pragma unroll
        for (int j = 0; j < 12; ++j) {
            float v = fmaxf(accp[j] + bs[c0 + j], 0.f);
            size_t idx = (size_t)gr * DIM + c0 + j;
            if (LAST) {
                if (obf)
                    ((__hip_bfloat16*)outLast)[idx] = __float2bfloat16(v);
                else
                    ((float*)outLast)[idx] = v;
            } else {
                outF[idx] = v * ns;  // pre-fold normS for next layer's gather
            }
        }
    }
}

// ---------------- host launch ----------------

extern "C" void kernel_launch(void* const* d_in, const int* in_sizes, int n_in,
                              void* d_out, int out_size, void* d_ws, size_t ws_size,
                              hipStream_t stream) {
    const void* h = d_in[0];
    const int* src = (const int*)d_in[1];
    const int* dst = (const int*)d_in[2];
    const void* Wt[3] = {d_in[3], d_in[5], d_in[7]};
    const void* bt[3] = {d_in[4], d_in[6], d_in[8]};

    // workspace layout (4B units)
    int* flags = (int*)d_ws;                        // 4
    int* degS = flags + 4;                          // 50000
    int* degD = degS + N_NODES;                     // 50000
    float* normS = (float*)(degD + N_NODES);        // 50000
    float* normD = normS + N_NODES;                 // 50000
    int* rowptr = (int*)(normD + N_NODES);          // 50001
    int* psum = rowptr + N_NODES + 1;               // 64
    int* poff = psum + 64;                          // 64
    int* eslot = poff + 64;                         // 800000
    int* esrc = eslot + N_EDGES;                    // 800000
    float* A = (float*)(esrc + N_EDGES);            // 4.8M
    float* Bnext = A + (size_t)N_NODES * DIM;       // 4.8M (ping-pong)

    detect_kernel<<<1, 64, 0, stream>>>((const unsigned*)h, (const unsigned*)d_in[3],
                                        (const unsigned*)src, flags);

    hipMemsetAsync(degS, 0, 2 * N_NODES * sizeof(int), stream);
    deg_kernel<<<(N_EDGES + 255) / 256, 256, 0, stream>>>(src, dst, degS, degD, eslot, flags);
    scan_p1<<<SCAN_NB, 256, 0, stream>>>(degS, degD, normS, normD, psum);
    scan_p2<<<1, 64, 0, stream>>>(psum, poff);
    scan_p3<<<SCAN_NB, 256, 0, stream>>>(degD, poff, rowptr);
    place_kernel<<<(N_EDGES + 255) / 256, 256, 0, stream>>>(src, dst, rowptr, eslot, esrc, flags);

    const int fgrid = (N_NODES + 63) / 64;
    fused_kernel<true, false><<<fgrid, 256, 0, stream>>>(h, normS, normD, rowptr, esrc,
                                                         Wt[0], bt[0], A, nullptr, flags);
    fused_kernel<false, false><<<fgrid, 256, 0, stream>>>(A, normS, normD, rowptr, esrc,
                                                          Wt[1], bt[1], Bnext, nullptr, flags);
    fused_kernel<false, true><<<fgrid, 256, 0, stream>>>(Bnext, normS, normD, rowptr, esrc,
                                                         Wt[2], bt[2], nullptr, d_out, flags);
}

// Round 7
// 448.740 us; speedup vs baseline: 1.5372x; 1.5372x over previous
//
#include <hip/hip_runtime.h>
#include <hip/hip_bf16.h>

#define N_NODES 50000
#define N_EDGES 800000
#define DIM 96
#define CH 24  // DIM/4 float4 chunks per row

#define SCAN_CHUNK 1024
#define SCAN_NB ((N_NODES + SCAN_CHUNK - 1) / SCAN_CHUNK)  // 49

// ---------------- dtype detection (on-device, graph-capture safe) ----------------
// flags[0] = h is bf16, flags[1] = W/b are bf16, flags[2] = indices are int64
// Measured R3-R6: this instance is fp32 + int64; detector kept for safety.

__global__ void detect_kernel(const unsigned* __restrict__ hw,
                              const unsigned* __restrict__ ww,
                              const unsigned* __restrict__ sw,
                              int* __restrict__ flags) {
    int t = threadIdx.x;
    if (t == 0 || t == 1) {
        const unsigned* p = (t == 0) ? hw : ww;
        int good = 0;
        for (int i = 0; i < 128; ++i) {
            unsigned w = p[i];
            unsigned lo = w & 0xFFFFu, hi = w >> 16;
            unsigned e0 = (lo >> 7) & 0xFF, e1 = (hi >> 7) & 0xFF;
            if (lo == 0 || (e0 >= 100 && e0 <= 140)) ++good;
            if (hi == 0 || (e1 >= 100 && e1 <= 140)) ++good;
        }
        flags[t] = (good >= 226) ? 1 : 0;
    } else if (t == 2) {
        int zeros = 0;
        for (int i = 0; i < 64; ++i)
            if (sw[2 * i + 1] == 0u) ++zeros;
        flags[2] = (zeros >= 60) ? 1 : 0;
    }
}

__device__ __forceinline__ int load_idx(const int* __restrict__ p, int e, int is64) {
    return p[is64 ? (e << 1) : e];
}

// ---------------- degrees + dst slot (single atomic pass) ----------------
// eslot[e] = arrival order of edge e within its dst bucket -> atomic-free placement.

__global__ __launch_bounds__(256) void deg_kernel(const int* __restrict__ src,
                                                  const int* __restrict__ dst,
                                                  int* __restrict__ degS,
                                                  int* __restrict__ degD,
                                                  int* __restrict__ eslot,
                                                  const int* __restrict__ flags) {
    int is64 = flags[2];
    int e = blockIdx.x * 256 + threadIdx.x;
    if (e < N_EDGES) {
        atomicAdd(&degS[load_idx(src, e, is64)], 1);
        eslot[e] = atomicAdd(&degD[load_idx(dst, e, is64)], 1);
    }
}

// ---------------- hierarchical exclusive scan of degD -> rowptr (+ norms) ----------------

__global__ __launch_bounds__(256) void scan_p1(const int* __restrict__ degS,
                                               const int* __restrict__ degD,
                                               float* __restrict__ normS,
                                               float* __restrict__ normD,
                                               int* __restrict__ psum) {
    __shared__ int red[256];
    int b = blockIdx.x, t = threadIdx.x;
    int base = b * SCAN_CHUNK + t * 4;
    int s = 0;
#pragma unroll
    for (int i = 0; i < 4; ++i) {
        int idx = base + i;
        if (idx < N_NODES) {
            int dd = degD[idx];
            s += dd;
            normD[idx] = rsqrtf((float)max(dd, 1));
            normS[idx] = rsqrtf((float)max(degS[idx], 1));
        }
    }
    red[t] = s;
    __syncthreads();
    for (int off = 128; off > 0; off >>= 1) {
        if (t < off) red[t] += red[t + off];
        __syncthreads();
    }
    if (t == 0) psum[b] = red[0];
}

__global__ __launch_bounds__(64) void scan_p2(const int* __restrict__ psum,
                                              int* __restrict__ poff) {
    __shared__ int s[64];
    int t = threadIdx.x;
    int v = (t < SCAN_NB) ? psum[t] : 0;
    s[t] = v;
    __syncthreads();
    for (int off = 1; off < 64; off <<= 1) {
        int u = (t >= off) ? s[t - off] : 0;
        __syncthreads();
        s[t] += u;
        __syncthreads();
    }
    if (t < SCAN_NB) poff[t] = s[t] - v;
}

__global__ __launch_bounds__(256) void scan_p3(const int* __restrict__ degD,
                                               const int* __restrict__ poff,
                                               int* __restrict__ rowptr) {
    __shared__ int s[256];
    int b = blockIdx.x, t = threadIdx.x;
    int base = b * SCAN_CHUNK + t * 4;
    int d[4];
    int tsum = 0;
#pragma unroll
    for (int i = 0; i < 4; ++i) {
        int idx = base + i;
        d[i] = (idx < N_NODES) ? degD[idx] : 0;
        tsum += d[i];
    }
    s[t] = tsum;
    __syncthreads();
    for (int off = 1; off < 256; off <<= 1) {
        int u = (t >= off) ? s[t - off] : 0;
        __syncthreads();
        s[t] += u;
        __syncthreads();
    }
    int run = poff[b] + s[t] - tsum;
#pragma unroll
    for (int i = 0; i < 4; ++i) {
        int idx = base + i;
        if (idx < N_NODES) { rowptr[idx] = run; run += d[i]; }
    }
    if (b == 0 && t == 0) rowptr[N_NODES] = N_EDGES;
}

// ---------------- atomic-free placement: esrc[rowptr[d]+eslot[e]] = s ----------------

__global__ __launch_bounds__(256) void place_kernel(const int* __restrict__ src,
                                                    const int* __restrict__ dst,
                                                    const int* __restrict__ rowptr,
                                                    const int* __restrict__ eslot,
                                                    int* __restrict__ esrc,
                                                    const int* __restrict__ flags) {
    int is64 = flags[2];
    int e = blockIdx.x * 256 + threadIdx.x;
    if (e < N_EDGES) {
        int d = load_idx(dst, e, is64);
        int s = load_idx(src, e, is64);
        esrc[rowptr[d] + eslot[e]] = s;
    }
}

// ---------------- gather: B[n] = normD[n] * sum_{e:dst=n} x[esrc[e]] (*normS if FIRST) ----------------
// 24 consecutive threads per node, one float4 chunk each; standalone kernel keeps
// occupancy high (8 VGPR, no LDS) so dependent-load latency is hidden by TLP.
// (R6 lesson: fusing this into the LDS-heavy GEMM block drops occupancy to 2
// blocks/CU and costs 1.6x.)

template <bool FIRST>
__global__ __launch_bounds__(256) void gather_kernel(const void* __restrict__ X,
                                                     const float* __restrict__ normS,
                                                     const float* __restrict__ normD,
                                                     const int* __restrict__ rowptr,
                                                     const int* __restrict__ esrc,
                                                     float* __restrict__ B,
                                                     const int* __restrict__ flags) {
    int g = blockIdx.x * 256 + threadIdx.x;
    if (g >= N_NODES * CH) return;
    int n = g / CH;
    int c = g - n * CH;
    int beg = rowptr[n], end = rowptr[n + 1];
    float4 acc = make_float4(0.f, 0.f, 0.f, 0.f);
    if (FIRST && flags[0]) {
        for (int k = beg; k < end; ++k) {
            int s = esrc[k];
            float ns = normS[s];
            const __hip_bfloat16* hp = (const __hip_bfloat16*)X + (size_t)s * DIM + c * 4;
            acc.x += __bfloat162float(hp[0]) * ns;
            acc.y += __bfloat162float(hp[1]) * ns;
            acc.z += __bfloat162float(hp[2]) * ns;
            acc.w += __bfloat162float(hp[3]) * ns;
        }
    } else if (FIRST) {
        for (int k = beg; k < end; ++k) {
            int s = esrc[k];
            float ns = normS[s];
            float4 v = ((const float4*)X)[s * CH + c];
            acc.x += v.x * ns; acc.y += v.y * ns;
            acc.z += v.z * ns; acc.w += v.w * ns;
        }
    } else {
        for (int k = beg; k < end; ++k) {
            int s = esrc[k];
            float4 v = ((const float4*)X)[s * CH + c];
            acc.x += v.x; acc.y += v.y; acc.z += v.z; acc.w += v.w;
        }
    }
    float nd = normD[n];
    acc.x *= nd; acc.y *= nd; acc.z *= nd; acc.w *= nd;
    ((float4*)B)[g] = acc;
}

// ---------------- GEMM: t = relu(M @ W + b); non-last: out = t*normS; last: d_out ----------------

template <bool LAST>
__global__ __launch_bounds__(256) void gemm_relu(const float* __restrict__ M,
                                                 const float* __restrict__ normS,
                                                 const void* __restrict__ W,
                                                 const void* __restrict__ bias,
                                                 float* __restrict__ outF,
                                                 void* __restrict__ outLast,
                                                 const int* __restrict__ flags) {
    __shared__ float Ws[DIM * DIM];
    __shared__ float Bs[64][DIM + 1];
    __shared__ float bs[DIM];

    int wbf = flags[1];
    if (wbf) {
        for (int i = threadIdx.x; i < DIM * DIM; i += 256)
            Ws[i] = __bfloat162float(((const __hip_bfloat16*)W)[i]);
        if (threadIdx.x < DIM)
            bs[threadIdx.x] = __bfloat162float(((const __hip_bfloat16*)bias)[threadIdx.x]);
    } else {
        for (int i = threadIdx.x; i < DIM * DIM; i += 256)
            Ws[i] = ((const float*)W)[i];
        if (threadIdx.x < DIM)
            bs[threadIdx.x] = ((const float*)bias)[threadIdx.x];
    }

    int row0 = blockIdx.x * 64;
    for (int i = threadIdx.x; i < 64 * CH; i += 256) {
        int r = i / CH;
        int c4 = i - r * CH;
        int gr = row0 + r;
        float4 v = make_float4(0.f, 0.f, 0.f, 0.f);
        if (gr < N_NODES) v = ((const float4*)M)[gr * CH + c4];
        float* bp = &Bs[r][c4 * 4];
        bp[0] = v.x; bp[1] = v.y; bp[2] = v.z; bp[3] = v.w;
    }
    __syncthreads();

    int cg = threadIdx.x & 7;
    int rg = threadIdx.x >> 3;
    int r0 = rg * 2;
    int c0 = cg * 12;

    float acc0[12], acc1[12];
#pragma unroll
    for (int j = 0; j < 12; ++j) { acc0[j] = 0.f; acc1[j] = 0.f; }

    for (int k = 0; k < DIM; ++k) {
        float a0 = Bs[r0][k];
        float a1 = Bs[r0 + 1][k];
        const float4* w4 = (const float4*)&Ws[k * DIM + c0];
#pragma unroll
        for (int j4 = 0; j4 < 3; ++j4) {
            float4 w = w4[j4];
            acc0[j4 * 4 + 0] += a0 * w.x;
            acc0[j4 * 4 + 1] += a0 * w.y;
            acc0[j4 * 4 + 2] += a0 * w.z;
            acc0[j4 * 4 + 3] += a0 * w.w;
            acc1[j4 * 4 + 0] += a1 * w.x;
            acc1[j4 * 4 + 1] += a1 * w.y;
            acc1[j4 * 4 + 2] += a1 * w.z;
            acc1[j4 * 4 + 3] += a1 * w.w;
        }
    }

    int obf = flags[0];
#pragma unroll
    for (int rr = 0; rr < 2; ++rr) {
        int gr = row0 + r0 + rr;
        if (gr >= N_NODES) continue;
        const float* accp = rr ? acc1 : acc0;
        float ns = LAST ? 1.f : normS[gr];
#pragma unroll
        for (int j = 0; j < 12; ++j) {
            float v = fmaxf(accp[j] + bs[c0 + j], 0.f);
            size_t idx = (size_t)gr * DIM + c0 + j;
            if (LAST) {
                if (obf)
                    ((__hip_bfloat16*)outLast)[idx] = __float2bfloat16(v);
                else
                    ((float*)outLast)[idx] = v;
            } else {
                outF[idx] = v * ns;  // pre-fold normS for next layer's gather
            }
        }
    }
}

// ---------------- host launch ----------------

extern "C" void kernel_launch(void* const* d_in, const int* in_sizes, int n_in,
                              void* d_out, int out_size, void* d_ws, size_t ws_size,
                              hipStream_t stream) {
    const void* h = d_in[0];
    const int* src = (const int*)d_in[1];
    const int* dst = (const int*)d_in[2];
    const void* Wt[3] = {d_in[3], d_in[5], d_in[7]};
    const void* bt[3] = {d_in[4], d_in[6], d_in[8]};

    // workspace layout (4B units)
    int* flags = (int*)d_ws;                        // 4
    int* degS = flags + 4;                          // 50000
    int* degD = degS + N_NODES;                     // 50000
    float* normS = (float*)(degD + N_NODES);        // 50000
    float* normD = normS + N_NODES;                 // 50000
    int* rowptr = (int*)(normD + N_NODES);          // 50001
    int* psum = rowptr + N_NODES + 1;               // 64
    int* poff = psum + 64;                          // 64
    int* eslot = poff + 64;                         // 800000
    int* esrc = eslot + N_EDGES;                    // 800000
    float* A = (float*)(esrc + N_EDGES);            // 4.8M
    float* Bm = A + (size_t)N_NODES * DIM;          // 4.8M

    detect_kernel<<<1, 64, 0, stream>>>((const unsigned*)h, (const unsigned*)d_in[3],
                                        (const unsigned*)src, flags);

    hipMemsetAsync(degS, 0, 2 * N_NODES * sizeof(int), stream);
    deg_kernel<<<(N_EDGES + 255) / 256, 256, 0, stream>>>(src, dst, degS, degD, eslot, flags);
    scan_p1<<<SCAN_NB, 256, 0, stream>>>(degS, degD, normS, normD, psum);
    scan_p2<<<1, 64, 0, stream>>>(psum, poff);
    scan_p3<<<SCAN_NB, 256, 0, stream>>>(degD, poff, rowptr);
    place_kernel<<<(N_EDGES + 255) / 256, 256, 0, stream>>>(src, dst, rowptr, eslot, esrc, flags);

    const int gather_grid = (N_NODES * CH + 255) / 256;
    const int gemm_grid = (N_NODES + 63) / 64;

    // layer 0: gather reads h directly (dtype-branched), normS applied per edge
    gather_kernel<true><<<gather_grid, 256, 0, stream>>>(h, normS, normD, rowptr, esrc, Bm, flags);
    gemm_relu<false><<<gemm_grid, 256, 0, stream>>>(Bm, normS, Wt[0], bt[0], A, nullptr, flags);
    // layer 1
    gather_kernel<false><<<gather_grid, 256, 0, stream>>>(A, normS, normD, rowptr, esrc, Bm, flags);
    gemm_relu<false><<<gemm_grid, 256, 0, stream>>>(Bm, normS, Wt[1], bt[1], A, nullptr, flags);
    // layer 2
    gather_kernel<false><<<gather_grid, 256, 0, stream>>>(A, normS, normD, rowptr, esrc, Bm, flags);
    gemm_relu<true><<<gemm_grid, 256, 0, stream>>>(Bm, normS, Wt[2], bt[2], nullptr, d_out, flags);
}

// Round 8
// 398.586 us; speedup vs baseline: 1.7307x; 1.1258x over previous
//
#include <hip/hip_runtime.h>
#include <hip/hip_bf16.h>

#define N_NODES 50000
#define N_EDGES 800000
#define DIM 96
#define CHB 12  // bf16 row = 96*2B = 12 x 16B chunks (8 features/thread)
#define CH 24   // fp32 row = 24 x float4 chunks (Bm)

#define SCAN_CHUNK 1024
#define SCAN_NB ((N_NODES + SCAN_CHUNK - 1) / SCAN_CHUNK)  // 49

// ---------------- dtype detection (on-device, graph-capture safe) ----------------
// flags[0] = h is bf16, flags[1] = W/b are bf16, flags[2] = indices are int64
// Measured R3-R7: this instance is fp32 + int64; detector kept for safety.

__global__ void detect_kernel(const unsigned* __restrict__ hw,
                              const unsigned* __restrict__ ww,
                              const unsigned* __restrict__ sw,
                              int* __restrict__ flags) {
    int t = threadIdx.x;
    if (t == 0 || t == 1) {
        const unsigned* p = (t == 0) ? hw : ww;
        int good = 0;
        for (int i = 0; i < 128; ++i) {
            unsigned w = p[i];
            unsigned lo = w & 0xFFFFu, hi = w >> 16;
            unsigned e0 = (lo >> 7) & 0xFF, e1 = (hi >> 7) & 0xFF;
            if (lo == 0 || (e0 >= 100 && e0 <= 140)) ++good;
            if (hi == 0 || (e1 >= 100 && e1 <= 140)) ++good;
        }
        flags[t] = (good >= 226) ? 1 : 0;
    } else if (t == 2) {
        int zeros = 0;
        for (int i = 0; i < 64; ++i)
            if (sw[2 * i + 1] == 0u) ++zeros;
        flags[2] = (zeros >= 60) ? 1 : 0;
    }
}

__device__ __forceinline__ int load_idx(const int* __restrict__ p, int e, int is64) {
    return p[is64 ? (e << 1) : e];
}

// round-to-nearest-even fp32 -> bf16 bits (finite inputs only)
__device__ __forceinline__ unsigned short f2bf(float f) {
    unsigned u = __float_as_uint(f);
    u += 0x7FFFu + ((u >> 16) & 1u);
    return (unsigned short)(u >> 16);
}

// ---------------- degrees + dst slot (single atomic pass) ----------------

__global__ __launch_bounds__(256) void deg_kernel(const int* __restrict__ src,
                                                  const int* __restrict__ dst,
                                                  int* __restrict__ degS,
                                                  int* __restrict__ degD,
                                                  int* __restrict__ eslot,
                                                  const int* __restrict__ flags) {
    int is64 = flags[2];
    int e = blockIdx.x * 256 + threadIdx.x;
    if (e < N_EDGES) {
        atomicAdd(&degS[load_idx(src, e, is64)], 1);
        eslot[e] = atomicAdd(&degD[load_idx(dst, e, is64)], 1);
    }
}

// ---------------- hierarchical exclusive scan of degD -> rowptr (+ norms) ----------------

__global__ __launch_bounds__(256) void scan_p1(const int* __restrict__ degS,
                                               const int* __restrict__ degD,
                                               float* __restrict__ normS,
                                               float* __restrict__ normD,
                                               int* __restrict__ psum) {
    __shared__ int red[256];
    int b = blockIdx.x, t = threadIdx.x;
    int base = b * SCAN_CHUNK + t * 4;
    int s = 0;
#pragma unroll
    for (int i = 0; i < 4; ++i) {
        int idx = base + i;
        if (idx < N_NODES) {
            int dd = degD[idx];
            s += dd;
            normD[idx] = rsqrtf((float)max(dd, 1));
            normS[idx] = rsqrtf((float)max(degS[idx], 1));
        }
    }
    red[t] = s;
    __syncthreads();
    for (int off = 128; off > 0; off >>= 1) {
        if (t < off) red[t] += red[t + off];
        __syncthreads();
    }
    if (t == 0) psum[b] = red[0];
}

__global__ __launch_bounds__(64) void scan_p2(const int* __restrict__ psum,
                                              int* __restrict__ poff) {
    __shared__ int s[64];
    int t = threadIdx.x;
    int v = (t < SCAN_NB) ? psum[t] : 0;
    s[t] = v;
    __syncthreads();
    for (int off = 1; off < 64; off <<= 1) {
        int u = (t >= off) ? s[t - off] : 0;
        __syncthreads();
        s[t] += u;
        __syncthreads();
    }
    if (t < SCAN_NB) poff[t] = s[t] - v;
}

__global__ __launch_bounds__(256) void scan_p3(const int* __restrict__ degD,
                                               const int* __restrict__ poff,
                                               int* __restrict__ rowptr) {
    __shared__ int s[256];
    int b = blockIdx.x, t = threadIdx.x;
    int base = b * SCAN_CHUNK + t * 4;
    int d[4];
    int tsum = 0;
#pragma unroll
    for (int i = 0; i < 4; ++i) {
        int idx = base + i;
        d[i] = (idx < N_NODES) ? degD[idx] : 0;
        tsum += d[i];
    }
    s[t] = tsum;
    __syncthreads();
    for (int off = 1; off < 256; off <<= 1) {
        int u = (t >= off) ? s[t - off] : 0;
        __syncthreads();
        s[t] += u;
        __syncthreads();
    }
    int run = poff[b] + s[t] - tsum;
#pragma unroll
    for (int i = 0; i < 4; ++i) {
        int idx = base + i;
        if (idx < N_NODES) { rowptr[idx] = run; run += d[i]; }
    }
    if (b == 0 && t == 0) rowptr[N_NODES] = N_EDGES;
}

// ---------------- atomic-free placement ----------------

__global__ __launch_bounds__(256) void place_kernel(const int* __restrict__ src,
                                                    const int* __restrict__ dst,
                                                    const int* __restrict__ rowptr,
                                                    const int* __restrict__ eslot,
                                                    int* __restrict__ esrc,
                                                    const int* __restrict__ flags) {
    int is64 = flags[2];
    int e = blockIdx.x * 256 + threadIdx.x;
    if (e < N_EDGES) {
        int d = load_idx(dst, e, is64);
        int s = load_idx(src, e, is64);
        esrc[rowptr[d] + eslot[e]] = s;
    }
}

// ---------------- cvt: A0 = bf16(h * normS)  (halves gather fetch bytes) ----------------

__global__ __launch_bounds__(256) void cvt_kernel(const void* __restrict__ h,
                                                  const float* __restrict__ normS,
                                                  unsigned short* __restrict__ out,
                                                  const int* __restrict__ flags) {
    int i4 = blockIdx.x * 256 + threadIdx.x;  // 4 elems per thread
    if (i4 >= N_NODES * DIM / 4) return;
    int i = i4 * 4;
    float ns = normS[i / DIM];  // DIM%4==0 -> all 4 elems same row
    float v0, v1, v2, v3;
    if (flags[0]) {
        const __hip_bfloat16* hp = (const __hip_bfloat16*)h + i;
        v0 = __bfloat162float(hp[0]); v1 = __bfloat162float(hp[1]);
        v2 = __bfloat162float(hp[2]); v3 = __bfloat162float(hp[3]);
    } else {
        float4 v = ((const float4*)h)[i4];
        v0 = v.x; v1 = v.y; v2 = v.z; v3 = v.w;
    }
    ushort4 o;
    o.x = f2bf(v0 * ns); o.y = f2bf(v1 * ns);
    o.z = f2bf(v2 * ns); o.w = f2bf(v3 * ns);
    ((ushort4*)out)[i4] = o;
}

// ---------------- gather: Bm[n] = normD[n] * sum_{e:dst=n} Abf[esrc[e]] ----------------
// 12 threads per node row, 8 features (one 16B uint4) each; fp32 accumulation.
// Standalone kernel keeps occupancy high so dependent-load latency hides via TLP
// (R6 lesson: fusing into the LDS-heavy GEMM costs 1.6x).

__global__ __launch_bounds__(256) void gather_kernel(const unsigned* __restrict__ Abf,
                                                     const float* __restrict__ normD,
                                                     const int* __restrict__ rowptr,
                                                     const int* __restrict__ esrc,
                                                     float* __restrict__ Bm) {
    int g = blockIdx.x * 256 + threadIdx.x;
    if (g >= N_NODES * CHB) return;
    int n = g / CHB;
    int c = g - n * CHB;
    int beg = rowptr[n], end = rowptr[n + 1];
    float a0 = 0.f, a1 = 0.f, a2 = 0.f, a3 = 0.f;
    float a4 = 0.f, a5 = 0.f, a6 = 0.f, a7 = 0.f;
    const uint4* Ap = (const uint4*)Abf;
    for (int k = beg; k < end; ++k) {
        int s = esrc[k];
        uint4 q = Ap[s * CHB + c];
        // each uint holds 2 bf16: low -> <<16, high -> mask
        a0 += __uint_as_float(q.x << 16);
        a1 += __uint_as_float(q.x & 0xFFFF0000u);
        a2 += __uint_as_float(q.y << 16);
        a3 += __uint_as_float(q.y & 0xFFFF0000u);
        a4 += __uint_as_float(q.z << 16);
        a5 += __uint_as_float(q.z & 0xFFFF0000u);
        a6 += __uint_as_float(q.w << 16);
        a7 += __uint_as_float(q.w & 0xFFFF0000u);
    }
    float nd = normD[n];
    float4 o0 = make_float4(a0 * nd, a1 * nd, a2 * nd, a3 * nd);
    float4 o1 = make_float4(a4 * nd, a5 * nd, a6 * nd, a7 * nd);
    ((float4*)Bm)[g * 2 + 0] = o0;
    ((float4*)Bm)[g * 2 + 1] = o1;
}

// ---------------- GEMM: t = relu(Bm @ W + b) ----------------
// non-last: outA = bf16(t * normS) for the next gather; last: d_out (fp32/bf16 per flag)

template <bool LAST>
__global__ __launch_bounds__(256) void gemm_relu(const float* __restrict__ M,
                                                 const float* __restrict__ normS,
                                                 const void* __restrict__ W,
                                                 const void* __restrict__ bias,
                                                 unsigned short* __restrict__ outA,
                                                 void* __restrict__ outLast,
                                                 const int* __restrict__ flags) {
    __shared__ float Ws[DIM * DIM];
    __shared__ float Bs[64][DIM + 1];
    __shared__ float bs[DIM];

    int wbf = flags[1];
    if (wbf) {
        for (int i = threadIdx.x; i < DIM * DIM; i += 256)
            Ws[i] = __bfloat162float(((const __hip_bfloat16*)W)[i]);
        if (threadIdx.x < DIM)
            bs[threadIdx.x] = __bfloat162float(((const __hip_bfloat16*)bias)[threadIdx.x]);
    } else {
        for (int i = threadIdx.x; i < DIM * DIM; i += 256)
            Ws[i] = ((const float*)W)[i];
        if (threadIdx.x < DIM)
            bs[threadIdx.x] = ((const float*)bias)[threadIdx.x];
    }

    int row0 = blockIdx.x * 64;
    for (int i = threadIdx.x; i < 64 * CH; i += 256) {
        int r = i / CH;
        int c4 = i - r * CH;
        int gr = row0 + r;
        float4 v = make_float4(0.f, 0.f, 0.f, 0.f);
        if (gr < N_NODES) v = ((const float4*)M)[gr * CH + c4];
        float* bp = &Bs[r][c4 * 4];
        bp[0] = v.x; bp[1] = v.y; bp[2] = v.z; bp[3] = v.w;
    }
    __syncthreads();

    int cg = threadIdx.x & 7;
    int rg = threadIdx.x >> 3;
    int r0 = rg * 2;
    int c0 = cg * 12;

    float acc0[12], acc1[12];
#pragma unroll
    for (int j = 0; j < 12; ++j) { acc0[j] = 0.f; acc1[j] = 0.f; }

    for (int k = 0; k < DIM; ++k) {
        float a0 = Bs[r0][k];
        float a1 = Bs[r0 + 1][k];
        const float4* w4 = (const float4*)&Ws[k * DIM + c0];
#pragma unroll
        for (int j4 = 0; j4 < 3; ++j4) {
            float4 w = w4[j4];
            acc0[j4 * 4 + 0] += a0 * w.x;
            acc0[j4 * 4 + 1] += a0 * w.y;
            acc0[j4 * 4 + 2] += a0 * w.z;
            acc0[j4 * 4 + 3] += a0 * w.w;
            acc1[j4 * 4 + 0] += a1 * w.x;
            acc1[j4 * 4 + 1] += a1 * w.y;
            acc1[j4 * 4 + 2] += a1 * w.z;
            acc1[j4 * 4 + 3] += a1 * w.w;
        }
    }

    int obf = flags[0];
#pragma unroll
    for (int rr = 0; rr < 2; ++rr) {
        int gr = row0 + r0 + rr;
        if (gr >= N_NODES) continue;
        const float* accp = rr ? acc1 : acc0;
        float ns = LAST ? 1.f : normS[gr];
#pragma unroll
        for (int j = 0; j < 12; ++j) {
            float v = fmaxf(accp[j] + bs[c0 + j], 0.f);
            size_t idx = (size_t)gr * DIM + c0 + j;
            if (LAST) {
                if (obf)
                    ((__hip_bfloat16*)outLast)[idx] = __float2bfloat16(v);
                else
                    ((float*)outLast)[idx] = v;
            } else {
                outA[idx] = f2bf(v * ns);  // bf16 activation, normS pre-folded
            }
        }
    }
}

// ---------------- host launch ----------------

extern "C" void kernel_launch(void* const* d_in, const int* in_sizes, int n_in,
                              void* d_out, int out_size, void* d_ws, size_t ws_size,
                              hipStream_t stream) {
    const void* h = d_in[0];
    const int* src = (const int*)d_in[1];
    const int* dst = (const int*)d_in[2];
    const void* Wt[3] = {d_in[3], d_in[5], d_in[7]};
    const void* bt[3] = {d_in[4], d_in[6], d_in[8]};

    // workspace layout (4B units)
    int* flags = (int*)d_ws;                        // 4
    int* degS = flags + 4;                          // 50000
    int* degD = degS + N_NODES;                     // 50000
    float* normS = (float*)(degD + N_NODES);        // 50000
    float* normD = normS + N_NODES;                 // 50000
    int* rowptr = (int*)(normD + N_NODES);          // 50001
    int* psum = rowptr + N_NODES + 1;               // 64
    int* poff = psum + 64;                          // 64
    int* eslot = poff + 64;                         // 800000
    int* esrc = eslot + N_EDGES;                    // 800000
    float* Bm = (float*)(esrc + N_EDGES);           // 4.8M floats (fp32 aggregate)
    unsigned short* A0 = (unsigned short*)(Bm + (size_t)N_NODES * DIM);  // 4.8M bf16
    unsigned short* A1 = A0 + (size_t)N_NODES * DIM;                     // 4.8M bf16

    detect_kernel<<<1, 64, 0, stream>>>((const unsigned*)h, (const unsigned*)d_in[3],
                                        (const unsigned*)src, flags);

    hipMemsetAsync(degS, 0, 2 * N_NODES * sizeof(int), stream);
    deg_kernel<<<(N_EDGES + 255) / 256, 256, 0, stream>>>(src, dst, degS, degD, eslot, flags);
    scan_p1<<<SCAN_NB, 256, 0, stream>>>(degS, degD, normS, normD, psum);
    scan_p2<<<1, 64, 0, stream>>>(psum, poff);
    scan_p3<<<SCAN_NB, 256, 0, stream>>>(degD, poff, rowptr);
    place_kernel<<<(N_EDGES + 255) / 256, 256, 0, stream>>>(src, dst, rowptr, eslot, esrc, flags);

    cvt_kernel<<<(N_NODES * DIM / 4 + 255) / 256, 256, 0, stream>>>(h, normS, A0, flags);

    const int gather_grid = (N_NODES * CHB + 255) / 256;
    const int gemm_grid = (N_NODES + 63) / 64;

    // layer 0
    gather_kernel<<<gather_grid, 256, 0, stream>>>((const unsigned*)A0, normD, rowptr, esrc, Bm);
    gemm_relu<false><<<gemm_grid, 256, 0, stream>>>(Bm, normS, Wt[0], bt[0], A1, nullptr, flags);
    // layer 1
    gather_kernel<<<gather_grid, 256, 0, stream>>>((const unsigned*)A1, normD, rowptr, esrc, Bm);
    gemm_relu<false><<<gemm_grid, 256, 0, stream>>>(Bm, normS, Wt[1], bt[1], A0, nullptr, flags);
    // layer 2
    gather_kernel<<<gather_grid, 256, 0, stream>>>((const unsigned*)A0, normD, rowptr, esrc, Bm);
    gemm_relu<true><<<gemm_grid, 256, 0, stream>>>(Bm, normS, Wt[2], bt[2], nullptr, d_out, flags);
}

// Round 9
// 336.056 us; speedup vs baseline: 2.0527x; 1.1861x over previous
//
#include <hip/hip_runtime.h>
#include <hip/hip_bf16.h>

#define N_NODES 50000
#define N_EDGES 800000
#define DIM 96
#define CHB 12  // bf16 row = 96*2B = 12 x 16B chunks (8 features/thread)
#define CH 24   // fp32 row = 24 x float4 chunks (Bm)

#define EPB 2048                                   // edges per partition block
#define NB_E ((N_EDGES + EPB - 1) / EPB)           // 391
#define NBKT ((N_NODES + 255) / 256)               // 196 buckets of 256 nodes

// ---------------- dtype detection (on-device, graph-capture safe) ----------------
// flags[0] = h is bf16, flags[1] = W/b are bf16, flags[2] = indices are int64
// Measured R3-R8: this instance is fp32 + int64; detector kept for safety.

__global__ void detect_kernel(const unsigned* __restrict__ hw,
                              const unsigned* __restrict__ ww,
                              const unsigned* __restrict__ sw,
                              int* __restrict__ flags) {
    int t = threadIdx.x;
    if (t == 0 || t == 1) {
        const unsigned* p = (t == 0) ? hw : ww;
        int good = 0;
        for (int i = 0; i < 128; ++i) {
            unsigned w = p[i];
            unsigned lo = w & 0xFFFFu, hi = w >> 16;
            unsigned e0 = (lo >> 7) & 0xFF, e1 = (hi >> 7) & 0xFF;
            if (lo == 0 || (e0 >= 100 && e0 <= 140)) ++good;
            if (hi == 0 || (e1 >= 100 && e1 <= 140)) ++good;
        }
        flags[t] = (good >= 226) ? 1 : 0;
    } else if (t == 2) {
        int zeros = 0;
        for (int i = 0; i < 64; ++i)
            if (sw[2 * i + 1] == 0u) ++zeros;
        flags[2] = (zeros >= 60) ? 1 : 0;
    }
}

__device__ __forceinline__ int load_idx(const int* __restrict__ p, int e, int is64) {
    return p[is64 ? (e << 1) : e];
}

// round-to-nearest-even fp32 -> bf16 bits (finite inputs only)
__device__ __forceinline__ unsigned short f2bf(float f) {
    unsigned u = __float_as_uint(f);
    u += 0x7FFFu + ((u >> 16) & 1u);
    return (unsigned short)(u >> 16);
}

// ---------------- pass 1: per-block bucket counts (LDS histograms, no global atomics) ----

__global__ __launch_bounds__(256) void part_count(const int* __restrict__ src,
                                                  const int* __restrict__ dst,
                                                  int* __restrict__ cntD,
                                                  int* __restrict__ cntS,
                                                  const int* __restrict__ flags) {
    __shared__ int lcD[256], lcS[256];
    int b = blockIdx.x, t = threadIdx.x;
    lcD[t] = 0; lcS[t] = 0;
    __syncthreads();
    int is64 = flags[2];
    int base = b * EPB;
#pragma unroll
    for (int i = 0; i < EPB / 256; ++i) {
        int e = base + i * 256 + t;
        if (e < N_EDGES) {
            int d = load_idx(dst, e, is64);
            int s = load_idx(src, e, is64);
            atomicAdd(&lcD[d >> 8], 1);
            atomicAdd(&lcS[s >> 8], 1);
        }
    }
    __syncthreads();
    cntD[b * 256 + t] = lcD[t];
    cntS[b * 256 + t] = lcS[t];
}

// ---------------- pass 2a: per-bucket exclusive scan over blocks (in-place) ----------------
// one block per bucket k; scans cnt[b][k] over b, leaves exclusive offsets, emits totals.

__global__ __launch_bounds__(256) void scan_buckets(int* __restrict__ cntD,
                                                    int* __restrict__ cntS,
                                                    int* __restrict__ btotD,
                                                    int* __restrict__ btotS) {
    __shared__ int sm[256];
    int k = blockIdx.x, t = threadIdx.x;
    int b0 = 2 * t, b1 = 2 * t + 1;
    // dst matrix
    int v0 = (b0 < NB_E) ? cntD[b0 * 256 + k] : 0;
    int v1 = (b1 < NB_E) ? cntD[b1 * 256 + k] : 0;
    int pair = v0 + v1;
    sm[t] = pair;
    __syncthreads();
    for (int off = 1; off < 256; off <<= 1) {
        int u = (t >= off) ? sm[t - off] : 0;
        __syncthreads();
        sm[t] += u;
        __syncthreads();
    }
    int excl = sm[t] - pair;
    if (b0 < NB_E) cntD[b0 * 256 + k] = excl;
    if (b1 < NB_E) cntD[b1 * 256 + k] = excl + v0;
    if (t == 255) btotD[k] = sm[255];
    __syncthreads();
    // src matrix
    v0 = (b0 < NB_E) ? cntS[b0 * 256 + k] : 0;
    v1 = (b1 < NB_E) ? cntS[b1 * 256 + k] : 0;
    pair = v0 + v1;
    sm[t] = pair;
    __syncthreads();
    for (int off = 1; off < 256; off <<= 1) {
        int u = (t >= off) ? sm[t - off] : 0;
        __syncthreads();
        sm[t] += u;
        __syncthreads();
    }
    excl = sm[t] - pair;
    if (b0 < NB_E) cntS[b0 * 256 + k] = excl;
    if (b1 < NB_E) cntS[b1 * 256 + k] = excl + v0;
    if (t == 255) btotS[k] = sm[255];
}

// ---------------- pass 2b: bucket bases (exclusive scan of 256 totals, both sets) -------

__global__ __launch_bounds__(256) void scan_bases(const int* __restrict__ btotD,
                                                  const int* __restrict__ btotS,
                                                  int* __restrict__ bbaseD,
                                                  int* __restrict__ bbaseS) {
    __shared__ int sm[256];
    int t = threadIdx.x;
    int v = btotD[t];
    sm[t] = v;
    __syncthreads();
    for (int off = 1; off < 256; off <<= 1) {
        int u = (t >= off) ? sm[t - off] : 0;
        __syncthreads();
        sm[t] += u;
        __syncthreads();
    }
    bbaseD[t] = sm[t] - v;
    if (t == 255) bbaseD[256] = sm[255];
    __syncthreads();
    v = btotS[t];
    sm[t] = v;
    __syncthreads();
    for (int off = 1; off < 256; off <<= 1) {
        int u = (t >= off) ? sm[t - off] : 0;
        __syncthreads();
        sm[t] += u;
        __syncthreads();
    }
    bbaseS[t] = sm[t] - v;
    if (t == 255) bbaseS[256] = sm[255];
}

// ---------------- pass 3: scatter into buckets (LDS running counters only) ----------------
// epack = (dst&255)<<16 | src   (src < 65536); sloc = src&255 byte stream.

__global__ __launch_bounds__(256) void part_scatter(const int* __restrict__ src,
                                                    const int* __restrict__ dst,
                                                    const int* __restrict__ offD,
                                                    const int* __restrict__ offS,
                                                    const int* __restrict__ bbaseD,
                                                    const int* __restrict__ bbaseS,
                                                    unsigned* __restrict__ epack,
                                                    unsigned char* __restrict__ sloc,
                                                    const int* __restrict__ flags) {
    __shared__ int runD[256], runS[256];
    int b = blockIdx.x, t = threadIdx.x;
    runD[t] = bbaseD[t] + offD[b * 256 + t];
    runS[t] = bbaseS[t] + offS[b * 256 + t];
    __syncthreads();
    int is64 = flags[2];
    int base = b * EPB;
#pragma unroll
    for (int i = 0; i < EPB / 256; ++i) {
        int e = base + i * 256 + t;
        if (e < N_EDGES) {
            int d = load_idx(dst, e, is64);
            int s = load_idx(src, e, is64);
            int pd = atomicAdd(&runD[d >> 8], 1);
            epack[pd] = ((unsigned)(d & 255) << 16) | (unsigned)s;
            int ps = atomicAdd(&runS[s >> 8], 1);
            sloc[ps] = (unsigned char)(s & 255);
        }
    }
}

// ---------------- pass 4: per-bucket CSR build + normD + esrc placement ----------------

__global__ __launch_bounds__(256) void bucket_build(const unsigned* __restrict__ epack,
                                                    const int* __restrict__ bbaseD,
                                                    int* __restrict__ rowptr,
                                                    float* __restrict__ normD,
                                                    unsigned short* __restrict__ esrc) {
    __shared__ int cnt[256];
    __shared__ int scan[256];
    __shared__ int run[256];
    int k = blockIdx.x, t = threadIdx.x;
    int ebeg = bbaseD[k], eend = bbaseD[k + 1];
    cnt[t] = 0;
    __syncthreads();
    for (int e = ebeg + t; e < eend; e += 256)
        atomicAdd(&cnt[epack[e] >> 16], 1);
    __syncthreads();
    int v = cnt[t];
    scan[t] = v;
    __syncthreads();
    for (int off = 1; off < 256; off <<= 1) {
        int u = (t >= off) ? scan[t - off] : 0;
        __syncthreads();
        scan[t] += u;
        __syncthreads();
    }
    int excl = scan[t] - v;
    int n = k * 256 + t;
    if (n < N_NODES) {
        rowptr[n] = ebeg + excl;
        normD[n] = rsqrtf((float)max(v, 1));
    }
    run[t] = excl;
    __syncthreads();
    for (int e = ebeg + t; e < eend; e += 256) {
        unsigned p = epack[e];
        int dl = p >> 16;
        int slot = atomicAdd(&run[dl], 1);
        esrc[ebeg + slot] = (unsigned short)(p & 0xFFFFu);
    }
    if (k == NBKT - 1 && t == 0) rowptr[N_NODES] = N_EDGES;
}

// ---------------- pass 5: src histogram per bucket -> normS ----------------

__global__ __launch_bounds__(256) void src_hist(const unsigned char* __restrict__ sloc,
                                                const int* __restrict__ bbaseS,
                                                float* __restrict__ normS) {
    __shared__ int cnt[256];
    int k = blockIdx.x, t = threadIdx.x;
    cnt[t] = 0;
    __syncthreads();
    int ebeg = bbaseS[k], eend = bbaseS[k + 1];
    for (int e = ebeg + t; e < eend; e += 256)
        atomicAdd(&cnt[sloc[e]], 1);
    __syncthreads();
    int n = k * 256 + t;
    if (n < N_NODES) normS[n] = rsqrtf((float)max(cnt[t], 1));
}

// ---------------- cvt: A0 = bf16(h * normS) ----------------

__global__ __launch_bounds__(256) void cvt_kernel(const void* __restrict__ h,
                                                  const float* __restrict__ normS,
                                                  unsigned short* __restrict__ out,
                                                  const int* __restrict__ flags) {
    int i4 = blockIdx.x * 256 + threadIdx.x;  // 4 elems per thread
    if (i4 >= N_NODES * DIM / 4) return;
    int i = i4 * 4;
    float ns = normS[i / DIM];
    float v0, v1, v2, v3;
    if (flags[0]) {
        const __hip_bfloat16* hp = (const __hip_bfloat16*)h + i;
        v0 = __bfloat162float(hp[0]); v1 = __bfloat162float(hp[1]);
        v2 = __bfloat162float(hp[2]); v3 = __bfloat162float(hp[3]);
    } else {
        float4 v = ((const float4*)h)[i4];
        v0 = v.x; v1 = v.y; v2 = v.z; v3 = v.w;
    }
    ushort4 o;
    o.x = f2bf(v0 * ns); o.y = f2bf(v1 * ns);
    o.z = f2bf(v2 * ns); o.w = f2bf(v3 * ns);
    ((ushort4*)out)[i4] = o;
}

// ---------------- gather: Bm[n] = normD[n] * sum_{e:dst=n} Abf[esrc[e]] ----------------
// 12 threads per node row, 8 bf16 features (one 16B uint4) each; fp32 accumulation.
// Standalone (no LDS) keeps occupancy high -> latency hidden by TLP (R6 lesson).

__global__ __launch_bounds__(256) void gather_kernel(const unsigned* __restrict__ Abf,
                                                     const float* __restrict__ normD,
                                                     const int* __restrict__ rowptr,
                                                     const unsigned short* __restrict__ esrc,
                                                     float* __restrict__ Bm) {
    int g = blockIdx.x * 256 + threadIdx.x;
    if (g >= N_NODES * CHB) return;
    int n = g / CHB;
    int c = g - n * CHB;
    int beg = rowptr[n], end = rowptr[n + 1];
    float a0 = 0.f, a1 = 0.f, a2 = 0.f, a3 = 0.f;
    float a4 = 0.f, a5 = 0.f, a6 = 0.f, a7 = 0.f;
    const uint4* Ap = (const uint4*)Abf;
    for (int k = beg; k < end; ++k) {
        int s = esrc[k];
        uint4 q = Ap[s * CHB + c];
        a0 += __uint_as_float(q.x << 16);
        a1 += __uint_as_float(q.x & 0xFFFF0000u);
        a2 += __uint_as_float(q.y << 16);
        a3 += __uint_as_float(q.y & 0xFFFF0000u);
        a4 += __uint_as_float(q.z << 16);
        a5 += __uint_as_float(q.z & 0xFFFF0000u);
        a6 += __uint_as_float(q.w << 16);
        a7 += __uint_as_float(q.w & 0xFFFF0000u);
    }
    float nd = normD[n];
    ((float4*)Bm)[g * 2 + 0] = make_float4(a0 * nd, a1 * nd, a2 * nd, a3 * nd);
    ((float4*)Bm)[g * 2 + 1] = make_float4(a4 * nd, a5 * nd, a6 * nd, a7 * nd);
}

// ---------------- GEMM: t = relu(Bm @ W + b) ----------------
// non-last: outA = bf16(t * normS); last: d_out (fp32/bf16 per flag)

template <bool LAST>
__global__ __launch_bounds__(256) void gemm_relu(const float* __restrict__ M,
                                                 const float* __restrict__ normS,
                                                 const void* __restrict__ W,
                                                 const void* __restrict__ bias,
                                                 unsigned short* __restrict__ outA,
                                                 void* __restrict__ outLast,
                                                 const int* __restrict__ flags) {
    __shared__ float Ws[DIM * DIM];
    __shared__ float Bs[64][DIM + 1];
    __shared__ float bs[DIM];

    int wbf = flags[1];
    if (wbf) {
        for (int i = threadIdx.x; i < DIM * DIM; i += 256)
            Ws[i] = __bfloat162float(((const __hip_bfloat16*)W)[i]);
        if (threadIdx.x < DIM)
            bs[threadIdx.x] = __bfloat162float(((const __hip_bfloat16*)bias)[threadIdx.x]);
    } else {
        for (int i = threadIdx.x; i < DIM * DIM; i += 256)
            Ws[i] = ((const float*)W)[i];
        if (threadIdx.x < DIM)
            bs[threadIdx.x] = ((const float*)bias)[threadIdx.x];
    }

    int row0 = blockIdx.x * 64;
    for (int i = threadIdx.x; i < 64 * CH; i += 256) {
        int r = i / CH;
        int c4 = i - r * CH;
        int gr = row0 + r;
        float4 v = make_float4(0.f, 0.f, 0.f, 0.f);
        if (gr < N_NODES) v = ((const float4*)M)[gr * CH + c4];
        float* bp = &Bs[r][c4 * 4];
        bp[0] = v.x; bp[1] = v.y; bp[2] = v.z; bp[3] = v.w;
    }
    __syncthreads();

    int cg = threadIdx.x & 7;
    int rg = threadIdx.x >> 3;
    int r0 = rg * 2;
    int c0 = cg * 12;

    float acc0[12], acc1[12];
#pragma unroll
    for (int j = 0; j < 12; ++j) { acc0[j] = 0.f; acc1[j] = 0.f; }

    for (int k = 0; k < DIM; ++k) {
        float a0 = Bs[r0][k];
        float a1 = Bs[r0 + 1][k];
        const float4* w4 = (const float4*)&Ws[k * DIM + c0];
#pragma unroll
        for (int j4 = 0; j4 < 3; ++j4) {
            float4 w = w4[j4];
            acc0[j4 * 4 + 0] += a0 * w.x;
            acc0[j4 * 4 + 1] += a0 * w.y;
            acc0[j4 * 4 + 2] += a0 * w.z;
            acc0[j4 * 4 + 3] += a0 * w.w;
            acc1[j4 * 4 + 0] += a1 * w.x;
            acc1[j4 * 4 + 1] += a1 * w.y;
            acc1[j4 * 4 + 2] += a1 * w.z;
            acc1[j4 * 4 + 3] += a1 * w.w;
        }
    }

    int obf = flags[0];
#pragma unroll
    for (int rr = 0; rr < 2; ++rr) {
        int gr = row0 + r0 + rr;
        if (gr >= N_NODES) continue;
        const float* accp = rr ? acc1 : acc0;
        float ns = LAST ? 1.f : normS[gr];
#pragma unroll
        for (int j = 0; j < 12; ++j) {
            float v = fmaxf(accp[j] + bs[c0 + j], 0.f);
            size_t idx = (size_t)gr * DIM + c0 + j;
            if (LAST) {
                if (obf)
                    ((__hip_bfloat16*)outLast)[idx] = __float2bfloat16(v);
                else
                    ((float*)outLast)[idx] = v;
            } else {
                outA[idx] = f2bf(v * ns);  // bf16 activation, normS pre-folded
            }
        }
    }
}

// ---------------- host launch ----------------

extern "C" void kernel_launch(void* const* d_in, const int* in_sizes, int n_in,
                              void* d_out, int out_size, void* d_ws, size_t ws_size,
                              hipStream_t stream) {
    const void* h = d_in[0];
    const int* src = (const int*)d_in[1];
    const int* dst = (const int*)d_in[2];
    const void* Wt[3] = {d_in[3], d_in[5], d_in[7]};
    const void* bt[3] = {d_in[4], d_in[6], d_in[8]};

    // workspace layout (4B units)
    int* flags = (int*)d_ws;                           // 4
    int* cntD = flags + 4;                             // NB_E*256 = 100096
    int* cntS = cntD + NB_E * 256;                     // 100096
    int* btotD = cntS + NB_E * 256;                    // 256
    int* btotS = btotD + 256;                          // 256
    int* bbaseD = btotS + 256;                         // 260 (257 used)
    int* bbaseS = bbaseD + 260;                        // 260
    int* rowptr = bbaseS + 260;                        // 50004 (50001 used)
    float* normS = (float*)(rowptr + 50004);           // 50000
    float* normD = normS + N_NODES;                    // 50000
    unsigned* epack = (unsigned*)(normD + N_NODES);    // 800000
    unsigned char* sloc = (unsigned char*)(epack + N_EDGES);  // 800000 B = 200000 w
    unsigned short* esrc = (unsigned short*)(sloc + N_EDGES); // 800000 us = 400000 w
    float* Bm = (float*)(esrc + N_EDGES);              // 4.8M floats
    unsigned short* A0 = (unsigned short*)(Bm + (size_t)N_NODES * DIM);  // 4.8M bf16
    unsigned short* A1 = A0 + (size_t)N_NODES * DIM;                     // 4.8M bf16

    detect_kernel<<<1, 64, 0, stream>>>((const unsigned*)h, (const unsigned*)d_in[3],
                                        (const unsigned*)src, flags);

    part_count<<<NB_E, 256, 0, stream>>>(src, dst, cntD, cntS, flags);
    scan_buckets<<<256, 256, 0, stream>>>(cntD, cntS, btotD, btotS);
    scan_bases<<<1, 256, 0, stream>>>(btotD, btotS, bbaseD, bbaseS);
    part_scatter<<<NB_E, 256, 0, stream>>>(src, dst, cntD, cntS, bbaseD, bbaseS,
                                           epack, sloc, flags);
    bucket_build<<<NBKT, 256, 0, stream>>>(epack, bbaseD, rowptr, normD, esrc);
    src_hist<<<NBKT, 256, 0, stream>>>(sloc, bbaseS, normS);

    cvt_kernel<<<(N_NODES * DIM / 4 + 255) / 256, 256, 0, stream>>>(h, normS, A0, flags);

    const int gather_grid = (N_NODES * CHB + 255) / 256;
    const int gemm_grid = (N_NODES + 63) / 64;

    // layer 0
    gather_kernel<<<gather_grid, 256, 0, stream>>>((const unsigned*)A0, normD, rowptr, esrc, Bm);
    gemm_relu<false><<<gemm_grid, 256, 0, stream>>>(Bm, normS, Wt[0], bt[0], A1, nullptr, flags);
    // layer 1
    gather_kernel<<<gather_grid, 256, 0, stream>>>((const unsigned*)A1, normD, rowptr, esrc, Bm);
    gemm_relu<false><<<gemm_grid, 256, 0, stream>>>(Bm, normS, Wt[1], bt[1], A0, nullptr, flags);
    // layer 2
    gather_kernel<<<gather_grid, 256, 0, stream>>>((const unsigned*)A0, normD, rowptr, esrc, Bm);
    gemm_relu<true><<<gemm_grid, 256, 0, stream>>>(Bm, normS, Wt[2], bt[2], nullptr, d_out, flags);
}

// Round 10
// 290.794 us; speedup vs baseline: 2.3722x; 1.1556x over previous
//
#include <hip/hip_runtime.h>
#include <hip/hip_bf16.h>

#define N_NODES 50000
#define N_PAD 50048  // Bm rows padded so MFMA frag loads stay in-bounds
#define N_EDGES 800000
#define DIM 96
#define CHB 12  // bf16 row = 96*2B = 12 x 16B chunks (8 features/thread)

#define EPB 2048                                   // edges per partition block
#define NB_E ((N_EDGES + EPB - 1) / EPB)           // 391
#define NBKT ((N_NODES + 255) / 256)               // 196 buckets of 256 nodes

typedef __attribute__((ext_vector_type(8))) short short8;  // 8 bf16 = 4 VGPRs
typedef __attribute__((ext_vector_type(4))) float f32x4;

// ---------------- dtype detection (on-device, graph-capture safe) ----------------
// flags[0] = h is bf16, flags[1] = W/b are bf16, flags[2] = indices are int64
// Measured R3-R9: this instance is fp32 + int64; detector kept for safety.

__global__ void detect_kernel(const unsigned* __restrict__ hw,
                              const unsigned* __restrict__ ww,
                              const unsigned* __restrict__ sw,
                              int* __restrict__ flags) {
    int t = threadIdx.x;
    if (t == 0 || t == 1) {
        const unsigned* p = (t == 0) ? hw : ww;
        int good = 0;
        for (int i = 0; i < 128; ++i) {
            unsigned w = p[i];
            unsigned lo = w & 0xFFFFu, hi = w >> 16;
            unsigned e0 = (lo >> 7) & 0xFF, e1 = (hi >> 7) & 0xFF;
            if (lo == 0 || (e0 >= 100 && e0 <= 140)) ++good;
            if (hi == 0 || (e1 >= 100 && e1 <= 140)) ++good;
        }
        flags[t] = (good >= 226) ? 1 : 0;
    } else if (t == 2) {
        int zeros = 0;
        for (int i = 0; i < 64; ++i)
            if (sw[2 * i + 1] == 0u) ++zeros;
        flags[2] = (zeros >= 60) ? 1 : 0;
    }
}

__device__ __forceinline__ int load_idx(const int* __restrict__ p, int e, int is64) {
    return p[is64 ? (e << 1) : e];
}

// round-to-nearest-even fp32 -> bf16 bits (finite inputs only)
__device__ __forceinline__ unsigned short f2bf(float f) {
    unsigned u = __float_as_uint(f);
    u += 0x7FFFu + ((u >> 16) & 1u);
    return (unsigned short)(u >> 16);
}

// ---------------- pass 1: per-block bucket counts (LDS histograms) ----------------

__global__ __launch_bounds__(256) void part_count(const int* __restrict__ src,
                                                  const int* __restrict__ dst,
                                                  int* __restrict__ cntD,
                                                  int* __restrict__ cntS,
                                                  const int* __restrict__ flags) {
    __shared__ int lcD[256], lcS[256];
    int b = blockIdx.x, t = threadIdx.x;
    lcD[t] = 0; lcS[t] = 0;
    __syncthreads();
    int is64 = flags[2];
    int base = b * EPB;
#pragma unroll
    for (int i = 0; i < EPB / 256; ++i) {
        int e = base + i * 256 + t;
        if (e < N_EDGES) {
            int d = load_idx(dst, e, is64);
            int s = load_idx(src, e, is64);
            atomicAdd(&lcD[d >> 8], 1);
            atomicAdd(&lcS[s >> 8], 1);
        }
    }
    __syncthreads();
    cntD[b * 256 + t] = lcD[t];
    cntS[b * 256 + t] = lcS[t];
}

// ---------------- pass 2a: per-bucket exclusive scan over blocks (in-place) --------

__global__ __launch_bounds__(256) void scan_buckets(int* __restrict__ cntD,
                                                    int* __restrict__ cntS,
                                                    int* __restrict__ btotD,
                                                    int* __restrict__ btotS) {
    __shared__ int sm[256];
    int k = blockIdx.x, t = threadIdx.x;
    int b0 = 2 * t, b1 = 2 * t + 1;
    int v0 = (b0 < NB_E) ? cntD[b0 * 256 + k] : 0;
    int v1 = (b1 < NB_E) ? cntD[b1 * 256 + k] : 0;
    int pair = v0 + v1;
    sm[t] = pair;
    __syncthreads();
    for (int off = 1; off < 256; off <<= 1) {
        int u = (t >= off) ? sm[t - off] : 0;
        __syncthreads();
        sm[t] += u;
        __syncthreads();
    }
    int excl = sm[t] - pair;
    if (b0 < NB_E) cntD[b0 * 256 + k] = excl;
    if (b1 < NB_E) cntD[b1 * 256 + k] = excl + v0;
    if (t == 255) btotD[k] = sm[255];
    __syncthreads();
    v0 = (b0 < NB_E) ? cntS[b0 * 256 + k] : 0;
    v1 = (b1 < NB_E) ? cntS[b1 * 256 + k] : 0;
    pair = v0 + v1;
    sm[t] = pair;
    __syncthreads();
    for (int off = 1; off < 256; off <<= 1) {
        int u = (t >= off) ? sm[t - off] : 0;
        __syncthreads();
        sm[t] += u;
        __syncthreads();
    }
    excl = sm[t] - pair;
    if (b0 < NB_E) cntS[b0 * 256 + k] = excl;
    if (b1 < NB_E) cntS[b1 * 256 + k] = excl + v0;
    if (t == 255) btotS[k] = sm[255];
}

// ---------------- pass 2b: bucket bases ----------------

__global__ __launch_bounds__(256) void scan_bases(const int* __restrict__ btotD,
                                                  const int* __restrict__ btotS,
                                                  int* __restrict__ bbaseD,
                                                  int* __restrict__ bbaseS) {
    __shared__ int sm[256];
    int t = threadIdx.x;
    int v = btotD[t];
    sm[t] = v;
    __syncthreads();
    for (int off = 1; off < 256; off <<= 1) {
        int u = (t >= off) ? sm[t - off] : 0;
        __syncthreads();
        sm[t] += u;
        __syncthreads();
    }
    bbaseD[t] = sm[t] - v;
    if (t == 255) bbaseD[256] = sm[255];
    __syncthreads();
    v = btotS[t];
    sm[t] = v;
    __syncthreads();
    for (int off = 1; off < 256; off <<= 1) {
        int u = (t >= off) ? sm[t - off] : 0;
        __syncthreads();
        sm[t] += u;
        __syncthreads();
    }
    bbaseS[t] = sm[t] - v;
    if (t == 255) bbaseS[256] = sm[255];
}

// ---------------- pass 3: scatter into buckets (LDS running counters) ----------------

__global__ __launch_bounds__(256) void part_scatter(const int* __restrict__ src,
                                                    const int* __restrict__ dst,
                                                    const int* __restrict__ offD,
                                                    const int* __restrict__ offS,
                                                    const int* __restrict__ bbaseD,
                                                    const int* __restrict__ bbaseS,
                                                    unsigned* __restrict__ epack,
                                                    unsigned char* __restrict__ sloc,
                                                    const int* __restrict__ flags) {
    __shared__ int runD[256], runS[256];
    int b = blockIdx.x, t = threadIdx.x;
    runD[t] = bbaseD[t] + offD[b * 256 + t];
    runS[t] = bbaseS[t] + offS[b * 256 + t];
    __syncthreads();
    int is64 = flags[2];
    int base = b * EPB;
#pragma unroll
    for (int i = 0; i < EPB / 256; ++i) {
        int e = base + i * 256 + t;
        if (e < N_EDGES) {
            int d = load_idx(dst, e, is64);
            int s = load_idx(src, e, is64);
            int pd = atomicAdd(&runD[d >> 8], 1);
            epack[pd] = ((unsigned)(d & 255) << 16) | (unsigned)s;
            int ps = atomicAdd(&runS[s >> 8], 1);
            sloc[ps] = (unsigned char)(s & 255);
        }
    }
}

// ---------------- pass 4: per-bucket CSR build + normD + esrc + src-hist -> normS ----

__global__ __launch_bounds__(256) void bucket_build(const unsigned* __restrict__ epack,
                                                    const int* __restrict__ bbaseD,
                                                    const unsigned char* __restrict__ sloc,
                                                    const int* __restrict__ bbaseS,
                                                    int* __restrict__ rowptr,
                                                    float* __restrict__ normD,
                                                    float* __restrict__ normS,
                                                    unsigned short* __restrict__ esrc) {
    __shared__ int cnt[256];
    __shared__ int scan[256];
    __shared__ int run[256];
    int k = blockIdx.x, t = threadIdx.x;
    int ebeg = bbaseD[k], eend = bbaseD[k + 1];
    cnt[t] = 0;
    __syncthreads();
    for (int e = ebeg + t; e < eend; e += 256)
        atomicAdd(&cnt[epack[e] >> 16], 1);
    __syncthreads();
    int v = cnt[t];
    scan[t] = v;
    __syncthreads();
    for (int off = 1; off < 256; off <<= 1) {
        int u = (t >= off) ? scan[t - off] : 0;
        __syncthreads();
        scan[t] += u;
        __syncthreads();
    }
    int excl = scan[t] - v;
    int n = k * 256 + t;
    if (n < N_NODES) {
        rowptr[n] = ebeg + excl;
        normD[n] = rsqrtf((float)max(v, 1));
    }
    run[t] = excl;
    __syncthreads();
    for (int e = ebeg + t; e < eend; e += 256) {
        unsigned p = epack[e];
        int dl = p >> 16;
        int slot = atomicAdd(&run[dl], 1);
        esrc[ebeg + slot] = (unsigned short)(p & 0xFFFFu);
    }
    if (k == NBKT - 1 && t == 0) rowptr[N_NODES] = N_EDGES;
    // ---- src histogram phase (merged src_hist) ----
    __syncthreads();
    cnt[t] = 0;
    __syncthreads();
    int sbeg = bbaseS[k], send = bbaseS[k + 1];
    for (int e = sbeg + t; e < send; e += 256)
        atomicAdd(&cnt[sloc[e]], 1);
    __syncthreads();
    if (n < N_NODES) normS[n] = rsqrtf((float)max(cnt[t], 1));
}

// ---------------- prep: W^T bf16 + bias fp32 for all 3 layers ----------------

__global__ __launch_bounds__(256) void prep_w(const void* __restrict__ W0,
                                              const void* __restrict__ W1,
                                              const void* __restrict__ W2,
                                              const void* __restrict__ b0,
                                              const void* __restrict__ b1,
                                              const void* __restrict__ b2,
                                              unsigned short* __restrict__ WT,
                                              float* __restrict__ biasc,
                                              const int* __restrict__ flags) {
    const void* Wp[3] = {W0, W1, W2};
    const void* bp[3] = {b0, b1, b2};
    int wbf = flags[1];
    for (int l = 0; l < 3; ++l) {
        for (int i = threadIdx.x; i < DIM * DIM; i += 256) {
            int k = i / DIM, n = i - k * DIM;
            float v = wbf ? __bfloat162float(((const __hip_bfloat16*)Wp[l])[i])
                          : ((const float*)Wp[l])[i];
            WT[l * DIM * DIM + n * DIM + k] = f2bf(v);
        }
        if (threadIdx.x < DIM) {
            float v = wbf ? __bfloat162float(((const __hip_bfloat16*)bp[l])[threadIdx.x])
                          : ((const float*)bp[l])[threadIdx.x];
            biasc[l * DIM + threadIdx.x] = v;
        }
    }
}

// ---------------- cvt: A0 = bf16(h * normS) ----------------

__global__ __launch_bounds__(256) void cvt_kernel(const void* __restrict__ h,
                                                  const float* __restrict__ normS,
                                                  unsigned short* __restrict__ out,
                                                  const int* __restrict__ flags) {
    int i4 = blockIdx.x * 256 + threadIdx.x;  // 4 elems per thread
    if (i4 >= N_NODES * DIM / 4) return;
    int i = i4 * 4;
    float ns = normS[i / DIM];
    float v0, v1, v2, v3;
    if (flags[0]) {
        const __hip_bfloat16* hp = (const __hip_bfloat16*)h + i;
        v0 = __bfloat162float(hp[0]); v1 = __bfloat162float(hp[1]);
        v2 = __bfloat162float(hp[2]); v3 = __bfloat162float(hp[3]);
    } else {
        float4 v = ((const float4*)h)[i4];
        v0 = v.x; v1 = v.y; v2 = v.z; v3 = v.w;
    }
    ushort4 o;
    o.x = f2bf(v0 * ns); o.y = f2bf(v1 * ns);
    o.z = f2bf(v2 * ns); o.w = f2bf(v3 * ns);
    ((ushort4*)out)[i4] = o;
}

// ---------------- gather: Bm[n] = bf16(normD[n] * sum Abf[esrc[e]]) ----------------
// 12 threads/row, 8 bf16 features (16B uint4) each; fp32 accumulation; unroll x2
// for load-level parallelism. Standalone (no LDS) keeps occupancy high (R6 lesson).

__global__ __launch_bounds__(256) void gather_kernel(const unsigned* __restrict__ Abf,
                                                     const float* __restrict__ normD,
                                                     const int* __restrict__ rowptr,
                                                     const unsigned short* __restrict__ esrc,
                                                     unsigned short* __restrict__ Bm) {
    int g = blockIdx.x * 256 + threadIdx.x;
    if (g >= N_NODES * CHB) return;
    int n = g / CHB;
    int c = g - n * CHB;
    int beg = rowptr[n], end = rowptr[n + 1];
    float a0 = 0.f, a1 = 0.f, a2 = 0.f, a3 = 0.f;
    float a4 = 0.f, a5 = 0.f, a6 = 0.f, a7 = 0.f;
    const uint4* Ap = (const uint4*)Abf;
    int k = beg;
    for (; k + 2 <= end; k += 2) {
        int s0 = esrc[k], s1 = esrc[k + 1];
        uint4 q = Ap[s0 * CHB + c];
        uint4 r = Ap[s1 * CHB + c];
        a0 += __uint_as_float(q.x << 16);
        a1 += __uint_as_float(q.x & 0xFFFF0000u);
        a2 += __uint_as_float(q.y << 16);
        a3 += __uint_as_float(q.y & 0xFFFF0000u);
        a4 += __uint_as_float(q.z << 16);
        a5 += __uint_as_float(q.z & 0xFFFF0000u);
        a6 += __uint_as_float(q.w << 16);
        a7 += __uint_as_float(q.w & 0xFFFF0000u);
        a0 += __uint_as_float(r.x << 16);
        a1 += __uint_as_float(r.x & 0xFFFF0000u);
        a2 += __uint_as_float(r.y << 16);
        a3 += __uint_as_float(r.y & 0xFFFF0000u);
        a4 += __uint_as_float(r.z << 16);
        a5 += __uint_as_float(r.z & 0xFFFF0000u);
        a6 += __uint_as_float(r.w << 16);
        a7 += __uint_as_float(r.w & 0xFFFF0000u);
    }
    if (k < end) {
        int s0 = esrc[k];
        uint4 q = Ap[s0 * CHB + c];
        a0 += __uint_as_float(q.x << 16);
        a1 += __uint_as_float(q.x & 0xFFFF0000u);
        a2 += __uint_as_float(q.y << 16);
        a3 += __uint_as_float(q.y & 0xFFFF0000u);
        a4 += __uint_as_float(q.z << 16);
        a5 += __uint_as_float(q.z & 0xFFFF0000u);
        a6 += __uint_as_float(q.w << 16);
        a7 += __uint_as_float(q.w & 0xFFFF0000u);
    }
    float nd = normD[n];
    uint4 o;
    o.x = (unsigned)f2bf(a0 * nd) | ((unsigned)f2bf(a1 * nd) << 16);
    o.y = (unsigned)f2bf(a2 * nd) | ((unsigned)f2bf(a3 * nd) << 16);
    o.z = (unsigned)f2bf(a4 * nd) | ((unsigned)f2bf(a5 * nd) << 16);
    o.w = (unsigned)f2bf(a6 * nd) | ((unsigned)f2bf(a7 * nd) << 16);
    ((uint4*)Bm)[g] = o;
}

// ---------------- MFMA GEMM: t = relu(Bm @ W + b) ----------------
// No LDS, no barriers. 4 waves/block, 16 output rows each. A-frags direct from
// global Bm (A[m=lane&15][k=quad*8+j]); B-frags from precomputed W^T bf16
// (B[n=lane&15][k=quad*8+j]); C/D: col=lane&15, row=quad*4+reg (m89/m91).
// non-last: outA = bf16(t*normS); last: d_out per flags[0].

template <bool LAST>
__global__ __launch_bounds__(256) void mfma_gemm(const unsigned short* __restrict__ Bm,
                                                 const float* __restrict__ normS,
                                                 const unsigned short* __restrict__ WT,
                                                 const float* __restrict__ biasc,
                                                 unsigned short* __restrict__ outA,
                                                 void* __restrict__ outLast,
                                                 const int* __restrict__ flags) {
    int wv = threadIdx.x >> 6;
    int lane = threadIdx.x & 63;
    int quad = lane >> 4;
    int ln = lane & 15;
    int rowbase = blockIdx.x * 64 + wv * 16;

    const short8* Ap = (const short8*)(Bm + (size_t)(rowbase + ln) * DIM + quad * 8);
    short8 a0 = Ap[0];   // k: quad*8 + [0,8)
    short8 a1 = Ap[4];   // +32
    short8 a2 = Ap[8];   // +64

    float ns[4];
    if (!LAST) {
#pragma unroll
        for (int r = 0; r < 4; ++r)
            ns[r] = normS[min(rowbase + quad * 4 + r, N_NODES - 1)];
    }
    int obf = flags[0];

#pragma unroll
    for (int ct = 0; ct < 6; ++ct) {
        const short8* Wp = (const short8*)(WT + (size_t)(ct * 16 + ln) * DIM + quad * 8);
        short8 b0 = Wp[0], b1 = Wp[4], b2 = Wp[8];
        f32x4 acc = {0.f, 0.f, 0.f, 0.f};
        acc = __builtin_amdgcn_mfma_f32_16x16x32_bf16(a0, b0, acc, 0, 0, 0);
        acc = __builtin_amdgcn_mfma_f32_16x16x32_bf16(a1, b1, acc, 0, 0, 0);
        acc = __builtin_amdgcn_mfma_f32_16x16x32_bf16(a2, b2, acc, 0, 0, 0);
        int col = ct * 16 + ln;
        float bv = biasc[col];
#pragma unroll
        for (int r = 0; r < 4; ++r) {
            int row = rowbase + quad * 4 + r;
            if (row < N_NODES) {
                float v = fmaxf(acc[r] + bv, 0.f);
                size_t idx = (size_t)row * DIM + col;
                if (LAST) {
                    if (obf)
                        ((__hip_bfloat16*)outLast)[idx] = __float2bfloat16(v);
                    else
                        ((float*)outLast)[idx] = v;
                } else {
                    outA[idx] = f2bf(v * ns[r]);
                }
            }
        }
    }
}

// ---------------- host launch ----------------

extern "C" void kernel_launch(void* const* d_in, const int* in_sizes, int n_in,
                              void* d_out, int out_size, void* d_ws, size_t ws_size,
                              hipStream_t stream) {
    const void* h = d_in[0];
    const int* src = (const int*)d_in[1];
    const int* dst = (const int*)d_in[2];

    // workspace layout (4B units; every offset stays 16B-aligned)
    int* flags = (int*)d_ws;                            // 4
    int* cntD = flags + 4;                              // 100096
    int* cntS = cntD + NB_E * 256;                      // 100096
    int* btotD = cntS + NB_E * 256;                     // 256
    int* btotS = btotD + 256;                           // 256
    int* bbaseD = btotS + 256;                          // 260
    int* bbaseS = bbaseD + 260;                         // 260
    int* rowptr = bbaseS + 260;                         // 50004
    float* normS = (float*)(rowptr + 50004);            // 50000
    float* normD = normS + N_NODES;                     // 50000
    unsigned short* WT = (unsigned short*)(normD + N_NODES);  // 3*9216 us = 13824 w
    float* biasc = (float*)(WT + 3 * DIM * DIM);        // 288
    unsigned* epack = (unsigned*)(biasc + 3 * DIM);     // 800000
    unsigned char* sloc = (unsigned char*)(epack + N_EDGES);   // 800000 B
    unsigned short* esrc = (unsigned short*)(sloc + N_EDGES);  // 800000 us
    unsigned short* Bm = esrc + N_EDGES;                // N_PAD*96 us
    unsigned short* A0 = Bm + (size_t)N_PAD * DIM;      // 4.8M us
    unsigned short* A1 = A0 + (size_t)N_NODES * DIM;    // 4.8M us

    detect_kernel<<<1, 64, 0, stream>>>((const unsigned*)h, (const unsigned*)d_in[3],
                                        (const unsigned*)src, flags);

    part_count<<<NB_E, 256, 0, stream>>>(src, dst, cntD, cntS, flags);
    scan_buckets<<<256, 256, 0, stream>>>(cntD, cntS, btotD, btotS);
    scan_bases<<<1, 256, 0, stream>>>(btotD, btotS, bbaseD, bbaseS);
    part_scatter<<<NB_E, 256, 0, stream>>>(src, dst, cntD, cntS, bbaseD, bbaseS,
                                           epack, sloc, flags);
    bucket_build<<<NBKT, 256, 0, stream>>>(epack, bbaseD, sloc, bbaseS,
                                           rowptr, normD, normS, esrc);
    prep_w<<<1, 256, 0, stream>>>(d_in[3], d_in[5], d_in[7], d_in[4], d_in[6], d_in[8],
                                  WT, biasc, flags);
    cvt_kernel<<<(N_NODES * DIM / 4 + 255) / 256, 256, 0, stream>>>(h, normS, A0, flags);

    const int gather_grid = (N_NODES * CHB + 255) / 256;
    const int gemm_grid = (N_NODES + 63) / 64;

    // layer 0
    gather_kernel<<<gather_grid, 256, 0, stream>>>((const unsigned*)A0, normD, rowptr, esrc, Bm);
    mfma_gemm<false><<<gemm_grid, 256, 0, stream>>>(Bm, normS, WT, biasc, A1, nullptr, flags);
    // layer 1
    gather_kernel<<<gather_grid, 256, 0, stream>>>((const unsigned*)A1, normD, rowptr, esrc, Bm);
    mfma_gemm<false><<<gemm_grid, 256, 0, stream>>>(Bm, normS, WT + DIM * DIM, biasc + DIM,
                                                    A0, nullptr, flags);
    // layer 2
    gather_kernel<<<gather_grid, 256, 0, stream>>>((const unsigned*)A0, normD, rowptr, esrc, Bm);
    mfma_gemm<true><<<gemm_grid, 256, 0, stream>>>(Bm, normS, WT + 2 * DIM * DIM, biasc + 2 * DIM,
                                                   nullptr, d_out, flags);
}

// Round 11
// 249.634 us; speedup vs baseline: 2.7633x; 1.1649x over previous
//
#include <hip/hip_runtime.h>
#include <hip/hip_bf16.h>

#define N_NODES 50000
#define N_PAD 50048  // Bm rows padded so MFMA frag loads stay in-bounds
#define N_EDGES 800000
#define DIM 96
#define CHB 12  // bf16 row = 96*2B = 12 x 16B chunks (8 features/thread)

#define EPB 2048                                   // edges per partition block
#define NB_E ((N_EDGES + EPB - 1) / EPB)           // 391
#define NBKT ((N_NODES + 255) / 256)               // 196 buckets of 256 nodes

typedef __attribute__((ext_vector_type(8))) short short8;  // 8 bf16 = 4 VGPRs
typedef __attribute__((ext_vector_type(4))) float f32x4;

// ---------------- dtype detection (on-device, graph-capture safe) ----------------
// flags[0] = h is bf16, flags[1] = W/b are bf16, flags[2] = indices are int64
// Measured R3-R10: this instance is fp32 + int64; detector kept for safety.
// Wave-parallel: 64 lanes x 2 words each, shfl reduction.

__device__ __forceinline__ int good_halves(unsigned w) {
    unsigned lo = w & 0xFFFFu, hi = w >> 16;
    unsigned e0 = (lo >> 7) & 0xFF, e1 = (hi >> 7) & 0xFF;
    int g = 0;
    if (lo == 0 || (e0 >= 100 && e0 <= 140)) ++g;
    if (hi == 0 || (e1 >= 100 && e1 <= 140)) ++g;
    return g;
}

__global__ void detect_kernel(const unsigned* __restrict__ hw,
                              const unsigned* __restrict__ ww,
                              const unsigned* __restrict__ sw,
                              int* __restrict__ flags) {
    int t = threadIdx.x;  // 64 threads = 1 wave
    int gh = good_halves(hw[t]) + good_halves(hw[64 + t]);
    int gw = good_halves(ww[t]) + good_halves(ww[64 + t]);
    int gz = (sw[2 * t + 1] == 0u) ? 1 : 0;
#pragma unroll
    for (int off = 32; off > 0; off >>= 1) {
        gh += __shfl_down(gh, off);
        gw += __shfl_down(gw, off);
        gz += __shfl_down(gz, off);
    }
    if (t == 0) {
        flags[0] = (gh >= 226) ? 1 : 0;
        flags[1] = (gw >= 226) ? 1 : 0;
        flags[2] = (gz >= 60) ? 1 : 0;
    }
}

__device__ __forceinline__ int load_idx(const int* __restrict__ p, int e, int is64) {
    return p[is64 ? (e << 1) : e];
}

// round-to-nearest-even fp32 -> bf16 bits (finite inputs only)
__device__ __forceinline__ unsigned short f2bf(float f) {
    unsigned u = __float_as_uint(f);
    u += 0x7FFFu + ((u >> 16) & 1u);
    return (unsigned short)(u >> 16);
}

// ---------------- pass 1: per-block bucket counts (LDS histograms) ----------------

__global__ __launch_bounds__(256) void part_count(const int* __restrict__ src,
                                                  const int* __restrict__ dst,
                                                  int* __restrict__ cntD,
                                                  int* __restrict__ cntS,
                                                  const int* __restrict__ flags) {
    __shared__ int lcD[256], lcS[256];
    int b = blockIdx.x, t = threadIdx.x;
    lcD[t] = 0; lcS[t] = 0;
    __syncthreads();
    int is64 = flags[2];
    int base = b * EPB;
#pragma unroll
    for (int i = 0; i < EPB / 256; ++i) {
        int e = base + i * 256 + t;
        if (e < N_EDGES) {
            int d = load_idx(dst, e, is64);
            int s = load_idx(src, e, is64);
            atomicAdd(&lcD[d >> 8], 1);
            atomicAdd(&lcS[s >> 8], 1);
        }
    }
    __syncthreads();
    cntD[b * 256 + t] = lcD[t];
    cntS[b * 256 + t] = lcS[t];
}

// ---------------- pass 2a: per-bucket exclusive scan over blocks (in-place) --------

__global__ __launch_bounds__(256) void scan_buckets(int* __restrict__ cntD,
                                                    int* __restrict__ cntS,
                                                    int* __restrict__ btotD,
                                                    int* __restrict__ btotS) {
    __shared__ int sm[256];
    int k = blockIdx.x, t = threadIdx.x;
    int b0 = 2 * t, b1 = 2 * t + 1;
    int v0 = (b0 < NB_E) ? cntD[b0 * 256 + k] : 0;
    int v1 = (b1 < NB_E) ? cntD[b1 * 256 + k] : 0;
    int pair = v0 + v1;
    sm[t] = pair;
    __syncthreads();
    for (int off = 1; off < 256; off <<= 1) {
        int u = (t >= off) ? sm[t - off] : 0;
        __syncthreads();
        sm[t] += u;
        __syncthreads();
    }
    int excl = sm[t] - pair;
    if (b0 < NB_E) cntD[b0 * 256 + k] = excl;
    if (b1 < NB_E) cntD[b1 * 256 + k] = excl + v0;
    if (t == 255) btotD[k] = sm[255];
    __syncthreads();
    v0 = (b0 < NB_E) ? cntS[b0 * 256 + k] : 0;
    v1 = (b1 < NB_E) ? cntS[b1 * 256 + k] : 0;
    pair = v0 + v1;
    sm[t] = pair;
    __syncthreads();
    for (int off = 1; off < 256; off <<= 1) {
        int u = (t >= off) ? sm[t - off] : 0;
        __syncthreads();
        sm[t] += u;
        __syncthreads();
    }
    excl = sm[t] - pair;
    if (b0 < NB_E) cntS[b0 * 256 + k] = excl;
    if (b1 < NB_E) cntS[b1 * 256 + k] = excl + v0;
    if (t == 255) btotS[k] = sm[255];
}

// ---------------- pass 2b: bucket bases ----------------

__global__ __launch_bounds__(256) void scan_bases(const int* __restrict__ btotD,
                                                  const int* __restrict__ btotS,
                                                  int* __restrict__ bbaseD,
                                                  int* __restrict__ bbaseS) {
    __shared__ int sm[256];
    int t = threadIdx.x;
    int v = btotD[t];
    sm[t] = v;
    __syncthreads();
    for (int off = 1; off < 256; off <<= 1) {
        int u = (t >= off) ? sm[t - off] : 0;
        __syncthreads();
        sm[t] += u;
        __syncthreads();
    }
    bbaseD[t] = sm[t] - v;
    if (t == 255) bbaseD[256] = sm[255];
    __syncthreads();
    v = btotS[t];
    sm[t] = v;
    __syncthreads();
    for (int off = 1; off < 256; off <<= 1) {
        int u = (t >= off) ? sm[t - off] : 0;
        __syncthreads();
        sm[t] += u;
        __syncthreads();
    }
    bbaseS[t] = sm[t] - v;
    if (t == 255) bbaseS[256] = sm[255];
}

// ---------------- pass 3: scatter into buckets (LDS running counters) ----------------

__global__ __launch_bounds__(256) void part_scatter(const int* __restrict__ src,
                                                    const int* __restrict__ dst,
                                                    const int* __restrict__ offD,
                                                    const int* __restrict__ offS,
                                                    const int* __restrict__ bbaseD,
                                                    const int* __restrict__ bbaseS,
                                                    unsigned* __restrict__ epack,
                                                    unsigned char* __restrict__ sloc,
                                                    const int* __restrict__ flags) {
    __shared__ int runD[256], runS[256];
    int b = blockIdx.x, t = threadIdx.x;
    runD[t] = bbaseD[t] + offD[b * 256 + t];
    runS[t] = bbaseS[t] + offS[b * 256 + t];
    __syncthreads();
    int is64 = flags[2];
    int base = b * EPB;
#pragma unroll
    for (int i = 0; i < EPB / 256; ++i) {
        int e = base + i * 256 + t;
        if (e < N_EDGES) {
            int d = load_idx(dst, e, is64);
            int s = load_idx(src, e, is64);
            int pd = atomicAdd(&runD[d >> 8], 1);
            epack[pd] = ((unsigned)(d & 255) << 16) | (unsigned)s;
            int ps = atomicAdd(&runS[s >> 8], 1);
            sloc[ps] = (unsigned char)(s & 255);
        }
    }
}

// ---------------- pass 4: per-bucket CSR build + normD + esrc + src-hist -> normS ----

__global__ __launch_bounds__(256) void bucket_build(const unsigned* __restrict__ epack,
                                                    const int* __restrict__ bbaseD,
                                                    const unsigned char* __restrict__ sloc,
                                                    const int* __restrict__ bbaseS,
                                                    int* __restrict__ rowptr,
                                                    float* __restrict__ normD,
                                                    float* __restrict__ normS,
                                                    unsigned short* __restrict__ esrc) {
    __shared__ int cnt[256];
    __shared__ int scan[256];
    __shared__ int run[256];
    int k = blockIdx.x, t = threadIdx.x;
    int ebeg = bbaseD[k], eend = bbaseD[k + 1];
    cnt[t] = 0;
    __syncthreads();
    for (int e = ebeg + t; e < eend; e += 256)
        atomicAdd(&cnt[epack[e] >> 16], 1);
    __syncthreads();
    int v = cnt[t];
    scan[t] = v;
    __syncthreads();
    for (int off = 1; off < 256; off <<= 1) {
        int u = (t >= off) ? scan[t - off] : 0;
        __syncthreads();
        scan[t] += u;
        __syncthreads();
    }
    int excl = scan[t] - v;
    int n = k * 256 + t;
    if (n < N_NODES) {
        rowptr[n] = ebeg + excl;
        normD[n] = rsqrtf((float)max(v, 1));
    }
    run[t] = excl;
    __syncthreads();
    for (int e = ebeg + t; e < eend; e += 256) {
        unsigned p = epack[e];
        int dl = p >> 16;
        int slot = atomicAdd(&run[dl], 1);
        esrc[ebeg + slot] = (unsigned short)(p & 0xFFFFu);
    }
    if (k == NBKT - 1 && t == 0) rowptr[N_NODES] = N_EDGES;
    // ---- src histogram phase (merged src_hist) ----
    __syncthreads();
    cnt[t] = 0;
    __syncthreads();
    int sbeg = bbaseS[k], send = bbaseS[k + 1];
    for (int e = sbeg + t; e < send; e += 256)
        atomicAdd(&cnt[sloc[e]], 1);
    __syncthreads();
    if (n < N_NODES) normS[n] = rsqrtf((float)max(cnt[t], 1));
}

// ---------------- prep: W^T bf16 + bias fp32, fully parallel (R10: 1-block = 55us) ----

__global__ __launch_bounds__(256) void prep_w(const void* __restrict__ W0,
                                              const void* __restrict__ W1,
                                              const void* __restrict__ W2,
                                              const void* __restrict__ b0,
                                              const void* __restrict__ b1,
                                              const void* __restrict__ b2,
                                              unsigned short* __restrict__ WT,
                                              float* __restrict__ biasc,
                                              const int* __restrict__ flags) {
    int idx = blockIdx.x * 256 + threadIdx.x;
    int wbf = flags[1];
    if (idx < 3 * DIM * DIM) {
        int l = idx / (DIM * DIM);
        int i = idx - l * DIM * DIM;
        int k = i / DIM, n = i - k * DIM;
        const void* Wp = (l == 0) ? W0 : (l == 1) ? W1 : W2;
        float v = wbf ? __bfloat162float(((const __hip_bfloat16*)Wp)[i])
                      : ((const float*)Wp)[i];
        WT[l * DIM * DIM + n * DIM + k] = f2bf(v);
    } else if (idx < 3 * DIM * DIM + 3 * DIM) {
        int j = idx - 3 * DIM * DIM;
        int l = j / DIM;
        int c = j - l * DIM;
        const void* bp = (l == 0) ? b0 : (l == 1) ? b1 : b2;
        float v = wbf ? __bfloat162float(((const __hip_bfloat16*)bp)[c])
                      : ((const float*)bp)[c];
        biasc[j] = v;
    }
}

// ---------------- cvt: A0 = bf16(h * normS) ----------------

__global__ __launch_bounds__(256) void cvt_kernel(const void* __restrict__ h,
                                                  const float* __restrict__ normS,
                                                  unsigned short* __restrict__ out,
                                                  const int* __restrict__ flags) {
    int i4 = blockIdx.x * 256 + threadIdx.x;  // 4 elems per thread
    if (i4 >= N_NODES * DIM / 4) return;
    int i = i4 * 4;
    float ns = normS[i / DIM];
    float v0, v1, v2, v3;
    if (flags[0]) {
        const __hip_bfloat16* hp = (const __hip_bfloat16*)h + i;
        v0 = __bfloat162float(hp[0]); v1 = __bfloat162float(hp[1]);
        v2 = __bfloat162float(hp[2]); v3 = __bfloat162float(hp[3]);
    } else {
        float4 v = ((const float4*)h)[i4];
        v0 = v.x; v1 = v.y; v2 = v.z; v3 = v.w;
    }
    ushort4 o;
    o.x = f2bf(v0 * ns); o.y = f2bf(v1 * ns);
    o.z = f2bf(v2 * ns); o.w = f2bf(v3 * ns);
    ((ushort4*)out)[i4] = o;
}

// ---------------- gather: Bm[n] = bf16(normD[n] * sum Abf[esrc[e]]) ----------------
// 12 threads/row, 8 bf16 features (16B uint4) each; fp32 accumulation; unroll x2.
// Standalone (no LDS) keeps occupancy high (R6 lesson).

__global__ __launch_bounds__(256) void gather_kernel(const unsigned* __restrict__ Abf,
                                                     const float* __restrict__ normD,
                                                     const int* __restrict__ rowptr,
                                                     const unsigned short* __restrict__ esrc,
                                                     unsigned short* __restrict__ Bm) {
    int g = blockIdx.x * 256 + threadIdx.x;
    if (g >= N_NODES * CHB) return;
    int n = g / CHB;
    int c = g - n * CHB;
    int beg = rowptr[n], end = rowptr[n + 1];
    float a0 = 0.f, a1 = 0.f, a2 = 0.f, a3 = 0.f;
    float a4 = 0.f, a5 = 0.f, a6 = 0.f, a7 = 0.f;
    const uint4* Ap = (const uint4*)Abf;
    int k = beg;
    for (; k + 2 <= end; k += 2) {
        int s0 = esrc[k], s1 = esrc[k + 1];
        uint4 q = Ap[s0 * CHB + c];
        uint4 r = Ap[s1 * CHB + c];
        a0 += __uint_as_float(q.x << 16);
        a1 += __uint_as_float(q.x & 0xFFFF0000u);
        a2 += __uint_as_float(q.y << 16);
        a3 += __uint_as_float(q.y & 0xFFFF0000u);
        a4 += __uint_as_float(q.z << 16);
        a5 += __uint_as_float(q.z & 0xFFFF0000u);
        a6 += __uint_as_float(q.w << 16);
        a7 += __uint_as_float(q.w & 0xFFFF0000u);
        a0 += __uint_as_float(r.x << 16);
        a1 += __uint_as_float(r.x & 0xFFFF0000u);
        a2 += __uint_as_float(r.y << 16);
        a3 += __uint_as_float(r.y & 0xFFFF0000u);
        a4 += __uint_as_float(r.z << 16);
        a5 += __uint_as_float(r.z & 0xFFFF0000u);
        a6 += __uint_as_float(r.w << 16);
        a7 += __uint_as_float(r.w & 0xFFFF0000u);
    }
    if (k < end) {
        int s0 = esrc[k];
        uint4 q = Ap[s0 * CHB + c];
        a0 += __uint_as_float(q.x << 16);
        a1 += __uint_as_float(q.x & 0xFFFF0000u);
        a2 += __uint_as_float(q.y << 16);
        a3 += __uint_as_float(q.y & 0xFFFF0000u);
        a4 += __uint_as_float(q.z << 16);
        a5 += __uint_as_float(q.z & 0xFFFF0000u);
        a6 += __uint_as_float(q.w << 16);
        a7 += __uint_as_float(q.w & 0xFFFF0000u);
    }
    float nd = normD[n];
    uint4 o;
    o.x = (unsigned)f2bf(a0 * nd) | ((unsigned)f2bf(a1 * nd) << 16);
    o.y = (unsigned)f2bf(a2 * nd) | ((unsigned)f2bf(a3 * nd) << 16);
    o.z = (unsigned)f2bf(a4 * nd) | ((unsigned)f2bf(a5 * nd) << 16);
    o.w = (unsigned)f2bf(a6 * nd) | ((unsigned)f2bf(a7 * nd) << 16);
    ((uint4*)Bm)[g] = o;
}

// ---------------- MFMA GEMM: t = relu(Bm @ W + b) ----------------
// No LDS, no barriers. 4 waves/block, 16 output rows each. A-frags direct from
// global Bm (A[m=lane&15][k=quad*8+j]); B-frags from precomputed W^T bf16
// (B[n=lane&15][k=quad*8+j]); C/D: col=lane&15, row=quad*4+reg (m89/m91).

template <bool LAST>
__global__ __launch_bounds__(256) void mfma_gemm(const unsigned short* __restrict__ Bm,
                                                 const float* __restrict__ normS,
                                                 const unsigned short* __restrict__ WT,
                                                 const float* __restrict__ biasc,
                                                 unsigned short* __restrict__ outA,
                                                 void* __restrict__ outLast,
                                                 const int* __restrict__ flags) {
    int wv = threadIdx.x >> 6;
    int lane = threadIdx.x & 63;
    int quad = lane >> 4;
    int ln = lane & 15;
    int rowbase = blockIdx.x * 64 + wv * 16;

    const short8* Ap = (const short8*)(Bm + (size_t)(rowbase + ln) * DIM + quad * 8);
    short8 a0 = Ap[0];   // k: quad*8 + [0,8)
    short8 a1 = Ap[4];   // +32
    short8 a2 = Ap[8];   // +64

    float ns[4];
    if (!LAST) {
#pragma unroll
        for (int r = 0; r < 4; ++r)
            ns[r] = normS[min(rowbase + quad * 4 + r, N_NODES - 1)];
    }
    int obf = flags[0];

#pragma unroll
    for (int ct = 0; ct < 6; ++ct) {
        const short8* Wp = (const short8*)(WT + (size_t)(ct * 16 + ln) * DIM + quad * 8);
        short8 b0 = Wp[0], b1 = Wp[4], b2 = Wp[8];
        f32x4 acc = {0.f, 0.f, 0.f, 0.f};
        acc = __builtin_amdgcn_mfma_f32_16x16x32_bf16(a0, b0, acc, 0, 0, 0);
        acc = __builtin_amdgcn_mfma_f32_16x16x32_bf16(a1, b1, acc, 0, 0, 0);
        acc = __builtin_amdgcn_mfma_f32_16x16x32_bf16(a2, b2, acc, 0, 0, 0);
        int col = ct * 16 + ln;
        float bv = biasc[col];
#pragma unroll
        for (int r = 0; r < 4; ++r) {
            int row = rowbase + quad * 4 + r;
            if (row < N_NODES) {
                float v = fmaxf(acc[r] + bv, 0.f);
                size_t idx = (size_t)row * DIM + col;
                if (LAST) {
                    if (obf)
                        ((__hip_bfloat16*)outLast)[idx] = __float2bfloat16(v);
                    else
                        ((float*)outLast)[idx] = v;
                } else {
                    outA[idx] = f2bf(v * ns[r]);
                }
            }
        }
    }
}

// ---------------- host launch ----------------

extern "C" void kernel_launch(void* const* d_in, const int* in_sizes, int n_in,
                              void* d_out, int out_size, void* d_ws, size_t ws_size,
                              hipStream_t stream) {
    const void* h = d_in[0];
    const int* src = (const int*)d_in[1];
    const int* dst = (const int*)d_in[2];

    // workspace layout (4B units; every offset stays 16B-aligned)
    int* flags = (int*)d_ws;                            // 4
    int* cntD = flags + 4;                              // 100096
    int* cntS = cntD + NB_E * 256;                      // 100096
    int* btotD = cntS + NB_E * 256;                     // 256
    int* btotS = btotD + 256;                           // 256
    int* bbaseD = btotS + 256;                          // 260
    int* bbaseS = bbaseD + 260;                         // 260
    int* rowptr = bbaseS + 260;                         // 50004
    float* normS = (float*)(rowptr + 50004);            // 50000
    float* normD = normS + N_NODES;                     // 50000
    unsigned short* WT = (unsigned short*)(normD + N_NODES);  // 3*9216 us
    float* biasc = (float*)(WT + 3 * DIM * DIM);        // 288
    unsigned* epack = (unsigned*)(biasc + 3 * DIM);     // 800000
    unsigned char* sloc = (unsigned char*)(epack + N_EDGES);   // 800000 B
    unsigned short* esrc = (unsigned short*)(sloc + N_EDGES);  // 800000 us
    unsigned short* Bm = esrc + N_EDGES;                // N_PAD*96 us
    unsigned short* A0 = Bm + (size_t)N_PAD * DIM;      // 4.8M us
    unsigned short* A1 = A0 + (size_t)N_NODES * DIM;    // 4.8M us

    detect_kernel<<<1, 64, 0, stream>>>((const unsigned*)h, (const unsigned*)d_in[3],
                                        (const unsigned*)src, flags);

    part_count<<<NB_E, 256, 0, stream>>>(src, dst, cntD, cntS, flags);
    scan_buckets<<<256, 256, 0, stream>>>(cntD, cntS, btotD, btotS);
    scan_bases<<<1, 256, 0, stream>>>(btotD, btotS, bbaseD, bbaseS);
    part_scatter<<<NB_E, 256, 0, stream>>>(src, dst, cntD, cntS, bbaseD, bbaseS,
                                           epack, sloc, flags);
    bucket_build<<<NBKT, 256, 0, stream>>>(epack, bbaseD, sloc, bbaseS,
                                           rowptr, normD, normS, esrc);
    prep_w<<<(3 * DIM * DIM + 3 * DIM + 255) / 256, 256, 0, stream>>>(
        d_in[3], d_in[5], d_in[7], d_in[4], d_in[6], d_in[8], WT, biasc, flags);
    cvt_kernel<<<(N_NODES * DIM / 4 + 255) / 256, 256, 0, stream>>>(h, normS, A0, flags);

    const int gather_grid = (N_NODES * CHB + 255) / 256;
    const int gemm_grid = (N_NODES + 63) / 64;

    // layer 0
    gather_kernel<<<gather_grid, 256, 0, stream>>>((const unsigned*)A0, normD, rowptr, esrc, Bm);
    mfma_gemm<false><<<gemm_grid, 256, 0, stream>>>(Bm, normS, WT, biasc, A1, nullptr, flags);
    // layer 1
    gather_kernel<<<gather_grid, 256, 0, stream>>>((const unsigned*)A1, normD, rowptr, esrc, Bm);
    mfma_gemm<false><<<gemm_grid, 256, 0, stream>>>(Bm, normS, WT + DIM * DIM, biasc + DIM,
                                                    A0, nullptr, flags);
    // layer 2
    gather_kernel<<<gather_grid, 256, 0, stream>>>((const unsigned*)A0, normD, rowptr, esrc, Bm);
    mfma_gemm<true><<<gemm_grid, 256, 0, stream>>>(Bm, normS, WT + 2 * DIM * DIM, biasc + 2 * DIM,
                                                   nullptr, d_out, flags);
}